// Round 12
// baseline (665.415 us; speedup 1.0000x reference)
//
#include <hip/hip_runtime.h>
#include <hip/hip_bf16.h>

typedef unsigned int u32;
typedef unsigned short u16;
typedef _Float16 f16;
typedef _Float16 f16x8 __attribute__((ext_vector_type(8)));
typedef float f32x4 __attribute__((ext_vector_type(4)));
typedef u32 u32x4 __attribute__((ext_vector_type(4)));

#define DEV static __device__ __forceinline__

// ---------- weight layout in ws (float offsets) ----------
#define O_G1   0        // gcn1_w  [10,64]
#define O_G1b  640      // gcn1_b  [64]
#define O_W1   704      // e_w1    [30,64]
#define O_B1   2624     // e_b1    [64]
#define O_W2   2688     // e_w2    [64,64] natural [k][o]
#define O_B2   6784     // e_b2    [64]
#define O_G2   6848     // gcn2_w  [128,64]
#define O_G2b  15040    // gcn2_b  [64]
#define O_G3   15104    // gcn3_w  [64,10]
#define O_G3b  15744    // gcn3_b  [10]
#define O_L1   15754    // l1_w    [20,10]
#define O_L1b  15954    // l1_b    [10]
#define O_L2t  15964    // l2_w^T  [128,10]
#define O_L2b  17244    // l2_b    [128]
#define O_L3   17372    // l3_w    [128,32]
#define O_L3b  21468    // l3_b    [32]
#define O_L4t  21500    // l4_w^T  [2,32]
#define O_L4b  21564    // l4_b    [2]
#define O_WF1  21568    // e_w1 f16 MFMA B-frags: 4 chunks x 64 lanes x 4 u32
#define O_WF2  22592    // e_w2 f16 MFMA B-frags: 4 chunks x 2 khalf x 4 q x 64 lanes
#define WTOT   24640

#define ECNB   32       // nodes per edgeconv block (32 -> 17.4KB LDS -> high blocks/CU)

DEV float bfu(u16 h){ return __uint_as_float(((u32)h) << 16); }
DEV float bflo(u32 u){ return __uint_as_float(u << 16); }
DEV float bfhi(u32 u){ return __uint_as_float(u & 0xffff0000u); }
DEV u16 f2bf(float x){
  __hip_bfloat16 b = __float2bfloat16(x);
  return *(u16*)&b;
}
DEV float rdf(const void* p, int idx, int isf32){
  return isf32 ? ((const float*)p)[idx] : bfu(((const u16*)p)[idx]);
}
DEV void load10_bf(const u32* __restrict__ p, float* f){
  u32 a0=p[0],a1=p[1],a2=p[2],a3=p[3],a4=p[4];
  f[0]=bflo(a0); f[1]=bfhi(a0);
  f[2]=bflo(a1); f[3]=bfhi(a1);
  f[4]=bflo(a2); f[5]=bfhi(a2);
  f[6]=bflo(a3); f[7]=bfhi(a3);
  f[8]=bflo(a4); f[9]=bfhi(a4);
}
DEV void load10_any(const void* base, size_t row, int isf32, float* f){
  if (isf32){
    const float* p = (const float*)base + row*10;
    #pragma unroll
    for (int k=0;k<10;k++) f[k] = p[k];
  } else {
    load10_bf((const u32*)base + row*5, f);
  }
}
// fast softplus: log1pf is a slow libm expansion; hw exp/log are accurate enough here
DEV float softplusf(float x){ return fmaxf(x,0.f) + __logf(1.f + __expf(-fabsf(x))); }

// A-tile K permutation: k-group g=0 -> x_i[0..8), g=1 -> x_j[0..8), g=2 -> ea[0..8),
// g=3 -> x_i[8],x_i[9],x_j[8],x_j[9],ea[8],ea[9],0,0.  Maps k -> row of e_w1 (30 rows).
DEV int permk(int k){
  if (k < 8)  return k;            // x_i 0..7  -> rows 0..7
  if (k < 16) return 10 + (k-8);   // x_j 0..7  -> rows 10..17
  if (k < 24) return 20 + (k-16);  // ea  0..7  -> rows 20..27
  if (k == 24) return 8;
  if (k == 25) return 9;
  if (k == 26) return 18;
  if (k == 27) return 19;
  if (k == 28) return 28;
  if (k == 29) return 29;
  return -1;                       // k=30,31 zero pad
}
DEV u32 packh2(float a, float b){
  union { f16 h[2]; u32 u; } t;
  t.h[0] = (f16)a; t.h[1] = (f16)b;
  return t.u;
}

// ---------- dtype detection: per-array bf16 vs fp32, one block per array ----------
__global__ __launch_bounds__(256) void k_detect(
    const u32* p0, const u32* p1, const u32* p2, const u32* p3,
    const u32* p4, const u32* p5, const u32* p6, const u32* p7,
    const u32* p8, const u32* p9, const u32* p10,const u32* p11,
    const u32* p12,const u32* p13,const u32* p14,const u32* p15,
    const u32* p16,const u32* p17,const u32* p18,const u32* p19,
    int* __restrict__ flags, int N_, int E_)
{
  int a = blockIdx.x;
  const u32* p;
  int elems;
  switch (a){
    case 0:  p=p0;  elems=N_*10; break;
    case 1:  p=p1;  elems=E_*10; break;
    case 2:  p=p2;  elems=640;  break;
    case 3:  p=p3;  elems=64;   break;
    case 4:  p=p4;  elems=1920; break;
    case 5:  p=p5;  elems=64;   break;
    case 6:  p=p6;  elems=4096; break;
    case 7:  p=p7;  elems=64;   break;
    case 8:  p=p8;  elems=8192; break;
    case 9:  p=p9;  elems=64;   break;
    case 10: p=p10; elems=640;  break;
    case 11: p=p11; elems=10;   break;
    case 12: p=p12; elems=200;  break;
    case 13: p=p13; elems=10;   break;
    case 14: p=p14; elems=1280; break;
    case 15: p=p15; elems=128;  break;
    case 16: p=p16; elems=4096; break;
    case 17: p=p17; elems=32;   break;
    case 18: p=p18; elems=64;   break;
    default: p=p19; elems=2;    break;
  }
  int nw = elems/2; if (nw > 512) nw = 512; if (nw < 1) nw = 1;
  int localA = 0, localZ = 0;
  for (int i=threadIdx.x; i<nw; i+=256){
    u32 w = p[i];
    u32 ex = (w >> 7) & 0xffu;
    if (ex >= 0x90u) localA++;
    if ((w & 0xffffu) == 0u) localZ++;
  }
  int packed = (localA << 16) | localZ;
  __shared__ int red[4];
  #pragma unroll
  for (int off=32; off; off>>=1) packed += __shfl_down(packed, off);
  if ((threadIdx.x & 63) == 0) red[threadIdx.x>>6] = packed;
  __syncthreads();
  if (threadIdx.x == 0){
    int s = red[0]+red[1]+red[2]+red[3];
    int sA = s >> 16, sZ = s & 0xffff;
    flags[a] = (sA * 16 >= nw || sZ * 4 >= nw * 3) ? 1 : 0;
  }
}

// ---------- weight prep ----------
__global__ __launch_bounds__(256) void k_prep(
    const void* g1w, const void* g1b, const void* ew1, const void* eb1,
    const void* ew2, const void* eb2, const void* g2w, const void* g2b,
    const void* g3w, const void* g3b, const void* l1w, const void* l1b,
    const void* l2w, const void* l2b, const void* l3w, const void* l3b,
    const void* l4w, const void* l4b,
    const int* __restrict__ flags, float* __restrict__ W)
{
  int t = threadIdx.x;
  int f2=flags[2],f3=flags[3],f4=flags[4],f5=flags[5],f6=flags[6],f7=flags[7];
  int f8=flags[8],f9=flags[9],f10=flags[10],f11=flags[11],f12=flags[12],f13=flags[13];
  int f14=flags[14],f15=flags[15],f16=flags[16],f17=flags[17],f18=flags[18],f19=flags[19];
  for (int i=t;i<640;i+=256)  W[O_G1+i]  = rdf(g1w,i,f2);
  for (int i=t;i<64;i+=256)   W[O_G1b+i] = rdf(g1b,i,f3);
  for (int i=t;i<1920;i+=256) W[O_W1+i]  = rdf(ew1,i,f4);
  for (int i=t;i<64;i+=256)   W[O_B1+i]  = rdf(eb1,i,f5);
  for (int i=t;i<4096;i+=256) W[O_W2+i]  = rdf(ew2,i,f6);   // natural [k][o]
  for (int i=t;i<64;i+=256)   W[O_B2+i]  = rdf(eb2,i,f7);
  for (int i=t;i<8192;i+=256) W[O_G2+i]  = rdf(g2w,i,f8);
  for (int i=t;i<64;i+=256)   W[O_G2b+i] = rdf(g2b,i,f9);
  for (int i=t;i<640;i+=256)  W[O_G3+i]  = rdf(g3w,i,f10);
  for (int i=t;i<10;i+=256)   W[O_G3b+i] = rdf(g3b,i,f11);
  for (int i=t;i<200;i+=256)  W[O_L1+i]  = rdf(l1w,i,f12);
  for (int i=t;i<10;i+=256)   W[O_L1b+i] = rdf(l1b,i,f13);
  for (int i=t;i<1280;i+=256){ int o=i/10,k=i-o*10; W[O_L2t+i]=rdf(l2w,k*128+o,f14); }
  for (int i=t;i<128;i+=256)  W[O_L2b+i] = rdf(l2b,i,f15);
  for (int i=t;i<4096;i+=256) W[O_L3+i]  = rdf(l3w,i,f16);
  for (int i=t;i<32;i+=256)   W[O_L3b+i] = rdf(l3b,i,f17);
  for (int i=t;i<64;i+=256){ int c=i>>5,j=i&31; W[O_L4t+i]=rdf(l4w,j*2+c,f18); }
  for (int i=t;i<2;i+=256)    W[O_L4b+i] = rdf(l4b,i,f19);
  // e_w1 MFMA B-fragments (f16, K-permuted, padded to K=32):
  u32* Wu = (u32*)W;
  for (int i=t;i<1024;i+=256){
    int l=i&63, q=(i>>6)&3, c=i>>8;
    int k0=(l>>4)*8+2*q, col=c*16+(l&15);
    int r0=permk(k0), r1=permk(k0+1);
    float v0 = (r0<0)?0.f:rdf(ew1,r0*64+col,f4);
    float v1 = (r1<0)?0.f:rdf(ew1,r1*64+col,f4);
    Wu[O_WF1+i] = packh2(v0,v1);
  }
  // e_w2 MFMA B-fragments: k-half h, kb = 32*h + (l>>4)*8
  for (int i=t;i<2048;i+=256){
    int l=i&63, q=(i>>6)&3, h2=(i>>8)&1, c=i>>9;
    int k0=32*h2+(l>>4)*8+2*q, col=c*16+(l&15);
    Wu[O_WF2+i] = packh2(rdf(ew2,k0*64+col,f6), rdf(ew2,(k0+1)*64+col,f6));
  }
}

// ---------- init: zero cnt ----------
__global__ __launch_bounds__(256) void k_init(int* __restrict__ cnt, int N_)
{
  int i = blockIdx.x*256 + threadIdx.x;
  if (i < N_) cnt[i] = 0;
}

// ---------- degree histogram over dst + per-edge rank (coalesced write) ----------
__global__ __launch_bounds__(256) void k_count(
    const int* __restrict__ ei, int* __restrict__ cnt,
    int* __restrict__ rank, int E_)
{
  int e = blockIdx.x*256 + threadIdx.x;
  if (e >= E_) return;
  rank[e] = atomicAdd(&cnt[ei[E_+e]], 1);
}

// ---------- per-1024-block sums ----------
__global__ __launch_bounds__(1024) void k_bsum(const int* __restrict__ cnt, int* __restrict__ bsum, int N_)
{
  int i = blockIdx.x*1024 + threadIdx.x;
  int v = (i < N_) ? cnt[i] : 0;
  #pragma unroll
  for (int off=32; off; off>>=1) v += __shfl_down(v, off);
  __shared__ int ws_[16];
  if ((threadIdx.x & 63) == 0) ws_[threadIdx.x>>6] = v;
  __syncthreads();
  if (threadIdx.x == 0){
    int s = 0;
    #pragma unroll
    for (int j=0;j<16;j++) s += ws_[j];
    bsum[blockIdx.x] = s;
  }
}

// ---------- exclusive scan of block sums (NB <= 128) ----------
__global__ __launch_bounds__(128) void k_scan_small(const int* __restrict__ bsum, int* __restrict__ boff, int NB)
{
  int t = threadIdx.x;
  int v = (t < NB) ? bsum[t] : 0;
  int lane = t & 63, w = t >> 6;
  int x = v;
  #pragma unroll
  for (int off=1; off<64; off<<=1){ int y=__shfl_up(x,off); if (lane>=off) x+=y; }
  __shared__ int t2[2];
  if (lane==63) t2[w]=x;
  __syncthreads();
  if (w==1) x += t2[0];
  boff[t] = x - v;
}

// ---------- final scan: row_ptr, dis ----------
__global__ __launch_bounds__(1024) void k_scan_final(
    int* __restrict__ cnt, const int* __restrict__ boff,
    int* __restrict__ rp, float* __restrict__ dis, int N_, int E_)
{
  int i = blockIdx.x*1024 + threadIdx.x;
  int v = (i < N_) ? cnt[i] : 0;
  int lane = threadIdx.x & 63, w = threadIdx.x >> 6;
  int x = v;
  #pragma unroll
  for (int off=1; off<64; off<<=1){ int y=__shfl_up(x,off); if (lane>=off) x+=y; }
  __shared__ int wp[16];
  if (lane==63) wp[w]=x;
  __syncthreads();
  if (threadIdx.x==0){
    int run=0;
    #pragma unroll
    for (int j=0;j<16;j++){ int t=wp[j]; wp[j]=run; run+=t; }
  }
  __syncthreads();
  int incl = x + wp[w] + boff[blockIdx.x];
  if (i < N_){
    rp[i]  = incl - v;
    dis[i] = rsqrtf(1.f + (float)v);
  }
  if (i == 0) rp[N_] = E_;
}

// ---------- CSR perm fill: scatter ONLY a 4B edge id ----------
__global__ __launch_bounds__(256) void k_fillpos(
    const int* __restrict__ ei, const int* __restrict__ rank,
    const int* __restrict__ rp, int* __restrict__ inv, int E_)
{
  int e = blockIdx.x*256 + threadIdx.x;
  if (e >= E_) return;
  int d = ei[E_+e];
  inv[rp[d] + rank[e]] = e;
}

// ---------- CSR materialize: {src,dst} int2 + edge_attr permuted to CSR order as f16 ----------
// The scattered edge_attr gather happens HERE (pure-throughput streaming kernel with
// massive TLP) instead of inside the MFMA edgeconv; edgeconv then reads ea2 coalesced.
__global__ __launch_bounds__(256) void k_fillcsr(
    const int* __restrict__ ei, const int* __restrict__ inv,
    const int* __restrict__ flags, const void* __restrict__ eav,
    int2* __restrict__ csr, u32* __restrict__ ea2, int E_)
{
  int p = blockIdx.x*256 + threadIdx.x;
  if (p >= E_) return;
  int e = inv[p];
  csr[p] = make_int2(ei[e], ei[E_+e]);     // {src, dst}
  int fea = flags[1];
  u32* o = ea2 + (size_t)p*5;
  if (fea){
    const float* q = (const float*)eav + (size_t)e*10;
    #pragma unroll
    for (int j=0;j<5;j++) o[j] = packh2(q[2*j], q[2*j+1]);
  } else {
    const u32* q = (const u32*)eav + (size_t)e*5;
    #pragma unroll
    for (int j=0;j<5;j++){ u32 w = q[j]; o[j] = packh2(bflo(w), bfhi(w)); }
  }
}

// ---------- EdgeConv via MFMA: block owns ECNB nodes, waves process 16-edge CSR tiles ----------
// ea comes from CSR-ordered f16 copy (coalesced); csr is int2 {src,dst}.
#define EC_EMIT \
  if (run >= 0){ int bb = run*64 + x; \
    atomicMax(&nodemax[bb],    __float_as_int(e0)); \
    atomicMax(&nodemax[bb+16], __float_as_int(e1)); \
    atomicMax(&nodemax[bb+32], __float_as_int(e2)); \
    atomicMax(&nodemax[bb+48], __float_as_int(e3)); }
#define EC_STEP(DD, RR) { \
  float t0=fmaxf(mcv[0][RR],0.f), t1=fmaxf(mcv[1][RR],0.f), \
        t2=fmaxf(mcv[2][RR],0.f), t3=fmaxf(mcv[3][RR],0.f); \
  if (DD == run){ e0=fmaxf(e0,t0); e1=fmaxf(e1,t1); e2=fmaxf(e2,t2); e3=fmaxf(e3,t3); } \
  else { EC_EMIT; run = DD; e0=t0; e1=t1; e2=t2; e3=t3; } }

__global__ __launch_bounds__(256) void k_edgeconv(
    const void* __restrict__ xv, const u32* __restrict__ ea2,
    const int* __restrict__ rp, const int2* __restrict__ csr,
    const float* __restrict__ W, const int* __restrict__ flags,
    float* __restrict__ oute, int N_, int E_)
{
  __shared__ int nodemax[ECNB*64];        // 8 KB: [local node][channel], float bits
  __shared__ u32 hbuf[4][16*36];          // per-wave h repack, 144 B row stride
  int tid = threadIdx.x;
  int l = tid & 63, wv = tid >> 6;
  int x = l & 15, g = l >> 4;
  int n0 = blockIdx.x * ECNB;
  if (n0 >= N_) return;
  int nend = n0 + ECNB; if (nend > N_) nend = N_;
  #pragma unroll
  for (int i=0;i<ECNB/4;i++) nodemax[i*256 + tid] = 0;
  int fx = flags[0];
  const u32* Wu = (const u32*)W;
  union FU { u32 u[4]; f16x8 v; };
  union HU { f16 h[8]; u32 u[4]; f16x8 v; };
  FU w1u[4];
  #pragma unroll
  for (int c=0;c<4;c++){
    #pragma unroll
    for (int q=0;q<4;q++) w1u[c].u[q] = Wu[O_WF1 + (c*4+q)*64 + l];
  }
  FU w2u[4][2];
  #pragma unroll
  for (int c=0;c<4;c++){
    #pragma unroll
    for (int h=0;h<2;h++){
      #pragma unroll
      for (int q=0;q<4;q++) w2u[c][h].u[q] = Wu[O_WF2 + ((c*2+h)*4+q)*64 + l];
    }
  }
  float b1v[4], b2v[4];
  #pragma unroll
  for (int c=0;c<4;c++){ b1v[c] = (W+O_B1)[c*16 + x]; b2v[c] = (W+O_B2)[c*16 + x]; }
  int pbase = rp[n0], pend = rp[nend];
  int ntiles = (pend - pbase + 15) >> 4;
  u32* hb = hbuf[wv];
  __syncthreads();

  for (int t = wv; t < ntiles; t += 4){
    int p0 = pbase + t*16;
    int eA = p0 + x; if (eA > E_-1) eA = E_-1;
    int2 ce = csr[eA];                    // {src, dst} — one 8B load
    HU af;
    u32 exv = 0;                          // f16 pair of row elements 8,9
    if (g == 2){
      const u32* q = ea2 + (size_t)eA*5;  // CSR-ordered, coalesced across the 16 lanes
      af.u[0]=q[0]; af.u[1]=q[1]; af.u[2]=q[2]; af.u[3]=q[3];
      exv = q[4];
    } else if (g < 2){
      long row = (g==0) ? (long)ce.y : (long)ce.x;   // dst : src
      if (fx){
        const float* p = (const float*)xv + row*10;
        #pragma unroll
        for (int j=0;j<8;j++) af.h[j] = (f16)p[j];
        exv = packh2(p[8], p[9]);
      } else {
        const u32* p = (const u32*)xv + row*5;
        u32 a0=p[0],a1=p[1],a2=p[2],a3=p[3],a4=p[4];
        af.h[0]=(f16)bflo(a0); af.h[1]=(f16)bfhi(a0);
        af.h[2]=(f16)bflo(a1); af.h[3]=(f16)bfhi(a1);
        af.h[4]=(f16)bflo(a2); af.h[5]=(f16)bfhi(a2);
        af.h[6]=(f16)bflo(a3); af.h[7]=(f16)bfhi(a3);
        exv = packh2(bflo(a4), bfhi(a4));
      }
    }
    // distribute elements 8..9 of the three rows of edge x to the g=3 lanes
    u32 ge0 = (u32)__shfl((int)exv, x);        // from g=0 lane: x_dst[8..9]
    u32 ge1 = (u32)__shfl((int)exv, x+16);     // from g=1 lane: x_src[8..9]
    u32 ge2 = (u32)__shfl((int)exv, x+32);     // from g=2 lane: ea[8..9]
    if (g == 3){ af.u[0]=ge0; af.u[1]=ge1; af.u[2]=ge2; af.u[3]=0; }
    // dst ids for this lane's 4 output edges via shfl of already-loaded ce.y
    int pe = p0 + 4*g;
    int dz = ce.y;
    int d0 = __shfl(dz, 4*g+0); d0 = (pe   < pend) ? d0 - n0 : -1;
    int d1 = __shfl(dz, 4*g+1); d1 = (pe+1 < pend) ? d1 - n0 : -1;
    int d2 = __shfl(dz, 4*g+2); d2 = (pe+2 < pend) ? d2 - n0 : -1;
    int d3 = __shfl(dz, 4*g+3); d3 = (pe+3 < pend) ? d3 - n0 : -1;
    // layer 1: h[16,64]
    f32x4 z = {0.f,0.f,0.f,0.f};
    f32x4 hc[4];
    #pragma unroll
    for (int c=0;c<4;c++)
      hc[c] = __builtin_amdgcn_mfma_f32_16x16x32_f16(af.v, w1u[c].v, z, 0, 0, 0);
    // bias+relu, pack f16 pairs across lane^1, write C-layout -> LDS rows
    #pragma unroll
    for (int r=0;r<4;r++){
      u32 pk0,pk1,pk2,pk3;
      {
        float hv = fmaxf(hc[0][r] + b1v[0], 0.f);
        union { f16 h; u16 u; } cv; cv.h=(f16)hv; u32 mine=cv.u;
        u32 other=(u32)__shfl_xor((int)mine,1,64);
        pk0 = (x&1) ? (other|(mine<<16)) : (mine|(other<<16));
      }{
        float hv = fmaxf(hc[1][r] + b1v[1], 0.f);
        union { f16 h; u16 u; } cv; cv.h=(f16)hv; u32 mine=cv.u;
        u32 other=(u32)__shfl_xor((int)mine,1,64);
        pk1 = (x&1) ? (other|(mine<<16)) : (mine|(other<<16));
      }{
        float hv = fmaxf(hc[2][r] + b1v[2], 0.f);
        union { f16 h; u16 u; } cv; cv.h=(f16)hv; u32 mine=cv.u;
        u32 other=(u32)__shfl_xor((int)mine,1,64);
        pk2 = (x&1) ? (other|(mine<<16)) : (mine|(other<<16));
      }{
        float hv = fmaxf(hc[3][r] + b1v[3], 0.f);
        union { f16 h; u16 u; } cv; cv.h=(f16)hv; u32 mine=cv.u;
        u32 other=(u32)__shfl_xor((int)mine,1,64);
        pk3 = (x&1) ? (other|(mine<<16)) : (mine|(other<<16));
      }
      int edge = 4*g + r;
      int par = (x&1) ? 16 : 0;
      hb[edge*36 + par + (x>>1)]     = (x&1) ? pk2 : pk0;   // chunks 0 / 2
      hb[edge*36 + 8 + par + (x>>1)] = (x&1) ? pk3 : pk1;   // chunks 1 / 3
    }
    asm volatile("s_waitcnt lgkmcnt(0)" ::: "memory");
    // read A2 fragments: row = x (edge), k = g*8 + 32*half
    HU a2f[2];
    #pragma unroll
    for (int h=0;h<2;h++){
      const u32x4* p = (const u32x4*)&hb[x*36 + g*4 + 16*h];
      u32x4 tv = *p;
      a2f[h].u[0]=tv[0]; a2f[h].u[1]=tv[1]; a2f[h].u[2]=tv[2]; a2f[h].u[3]=tv[3];
    }
    // layer 2: m[16,64] with bias in C-init
    f32x4 mcv[4];
    #pragma unroll
    for (int c=0;c<4;c++){
      f32x4 bi = {b2v[c],b2v[c],b2v[c],b2v[c]};
      f32x4 acc = __builtin_amdgcn_mfma_f32_16x16x32_f16(a2f[0].v, w2u[c][0].v, bi, 0, 0, 0);
      mcv[c]    = __builtin_amdgcn_mfma_f32_16x16x32_f16(a2f[1].v, w2u[c][1].v, acc, 0, 0, 0);
    }
    // CSR-run-merged segmented max into LDS node table
    int run = -2; float e0=0.f,e1=0.f,e2=0.f,e3=0.f;
    EC_STEP(d0,0) EC_STEP(d1,1) EC_STEP(d2,2) EC_STEP(d3,3)
    EC_EMIT;
  }
  __syncthreads();
  int tot = (nend - n0) * 64;
  for (int i = tid; i < tot; i += 256)
    oute[(size_t)n0*64 + i] = __int_as_float(nodemax[i]);
}

// ---------- FUSED gcn1 pre-agg + hw2: gather phase + MLP phase in one thread ----------
__global__ __launch_bounds__(256) void k_aggxhw2(
    const void* __restrict__ xv, const int* __restrict__ rp,
    const int2* __restrict__ csr, const float* __restrict__ dis,
    const int* __restrict__ flags, const float* __restrict__ oute,
    const float* __restrict__ W, u16* __restrict__ hw2o, int N_)
{
  int i = blockIdx.x*256 + threadIdx.x;
  if (i >= N_) return;
  int fx = flags[0];
  float di = dis[i], d2 = di*di;
  // ---- gather: sv = S*x row (stays in registers) ----
  float sv[10], ac2[10], tA[10], tB[10], tC[10], tD[10];
  load10_any(xv, (size_t)i, fx, tA);
  #pragma unroll
  for (int f=0;f<10;f++){ sv[f] = tA[f]*d2; ac2[f] = 0.f; }
  int b = rp[i], en = rp[i+1];
  int p = b;
  for (; p+3 < en; p += 4){
    int s0 = csr[p].x, s1 = csr[p+1].x, s2 = csr[p+2].x, s3 = csr[p+3].x;
    float m0 = dis[s0]*di, m1 = dis[s1]*di, m2 = dis[s2]*di, m3 = dis[s3]*di;
    load10_any(xv, (size_t)s0, fx, tA);
    load10_any(xv, (size_t)s1, fx, tB);
    load10_any(xv, (size_t)s2, fx, tC);
    load10_any(xv, (size_t)s3, fx, tD);
    #pragma unroll
    for (int f=0;f<10;f++){
      sv[f]  = fmaf(tA[f], m0, sv[f]);
      ac2[f] = fmaf(tB[f], m1, ac2[f]);
      sv[f]  = fmaf(tC[f], m2, sv[f]);
      ac2[f] = fmaf(tD[f], m3, ac2[f]);
    }
  }
  for (; p < en; p++){
    int s0 = csr[p].x; float m0 = dis[s0]*di;
    load10_any(xv, (size_t)s0, fx, tA);
    #pragma unroll
    for (int f=0;f<10;f++) sv[f] = fmaf(tA[f], m0, sv[f]);
  }
  #pragma unroll
  for (int f=0;f<10;f++) sv[f] += ac2[f];
  // ---- MLP: hw2 = relu(sv@G1+G1b)@G2top + oute@G2bot -> bf16 ----
  const float* __restrict__ G1  = W + O_G1;
  const float* __restrict__ G1b = W + O_G1b;
  const float* __restrict__ G2  = W + O_G2;
  float hw[64];
  #pragma unroll
  for (int f=0;f<64;f++) hw[f] = 0.f;
  #pragma unroll 1
  for (int k=0;k<64;k++){
    float o1 = G1b[k];
    #pragma unroll
    for (int j=0;j<10;j++) o1 = fmaf(sv[j], G1[j*64+k], o1);
    o1 = fmaxf(o1, 0.f);
    const float* __restrict__ wt = G2 + k*64;
    #pragma unroll
    for (int f=0;f<64;f++) hw[f] = fmaf(o1, wt[f], hw[f]);
  }
  const float* orow = oute + (size_t)i*64;
  #pragma unroll 1
  for (int k=0;k<64;k++){
    float ov = orow[k];
    const float* __restrict__ wb = G2 + (64+k)*64;
    #pragma unroll
    for (int f=0;f<64;f++) hw[f] = fmaf(ov, wb[f], hw[f]);
  }
  u16* out = hw2o + (size_t)i*64;
  #pragma unroll
  for (int f=0;f<64;f++) out[f] = f2bf(hw[f]);
}

// ---------- gcn2 aggregation: wave per node, 16 lanes x 4 edge slots, uint2 loads ----------
__global__ __launch_bounds__(256) void k_agg64(
    const u16* __restrict__ hw2, const int* __restrict__ rp,
    const int2* __restrict__ csr, const float* __restrict__ dis,
    const float* __restrict__ W, float* __restrict__ out2, int N_)
{
  int i = (blockIdx.x*256 + threadIdx.x) >> 6;
  int lane = threadIdx.x & 63;
  if (i >= N_) return;
  int e4 = lane >> 4, c4 = lane & 15;
  float di = dis[i];
  int b = rp[i], en = rp[i+1];
  const uint2* __restrict__ h2 = (const uint2*)hw2;   // row stride = 16 uint2
  float a0=0.f,a1=0.f,a2=0.f,a3=0.f;
  float b0=0.f,b1=0.f,b2=0.f,b3=0.f;
  int p = b + e4;
  int sA = (p   < en) ? csr[p].x   : 0;
  int sB = (p+4 < en) ? csr[p+4].x : 0;
  for (; p + 4 < en; p += 8){
    int sAn = (p+8  < en) ? csr[p+8].x  : 0;
    int sBn = (p+12 < en) ? csr[p+12].x : 0;
    float nmA = dis[sA]*di, nmB = dis[sB]*di;
    uint2 wA = h2[(size_t)sA*16 + c4];
    uint2 wB = h2[(size_t)sB*16 + c4];
    a0 = fmaf(bflo(wA.x), nmA, a0); a1 = fmaf(bfhi(wA.x), nmA, a1);
    a2 = fmaf(bflo(wA.y), nmA, a2); a3 = fmaf(bfhi(wA.y), nmA, a3);
    b0 = fmaf(bflo(wB.x), nmB, b0); b1 = fmaf(bfhi(wB.x), nmB, b1);
    b2 = fmaf(bflo(wB.y), nmB, b2); b3 = fmaf(bfhi(wB.y), nmB, b3);
    sA = sAn; sB = sBn;
  }
  if (p < en){
    float nmA = dis[sA]*di;
    uint2 wA = h2[(size_t)sA*16 + c4];
    a0 = fmaf(bflo(wA.x), nmA, a0); a1 = fmaf(bfhi(wA.x), nmA, a1);
    a2 = fmaf(bflo(wA.y), nmA, a2); a3 = fmaf(bfhi(wA.y), nmA, a3);
  }
  a0 += b0; a1 += b1; a2 += b2; a3 += b3;
  a0 += __shfl_xor(a0,16); a1 += __shfl_xor(a1,16);
  a2 += __shfl_xor(a2,16); a3 += __shfl_xor(a3,16);
  a0 += __shfl_xor(a0,32); a1 += __shfl_xor(a1,32);
  a2 += __shfl_xor(a2,32); a3 += __shfl_xor(a3,32);
  if (e4 == 0){
    uint2 ws2 = h2[(size_t)i*16 + c4];
    float d2 = di*di;
    const float* G2b = W + O_G2b;
    float4 o;
    o.x = fmaxf(fmaf(bflo(ws2.x), d2, a0) + G2b[4*c4],   0.f);
    o.y = fmaxf(fmaf(bfhi(ws2.x), d2, a1) + G2b[4*c4+1], 0.f);
    o.z = fmaxf(fmaf(bflo(ws2.y), d2, a2) + G2b[4*c4+2], 0.f);
    o.w = fmaxf(fmaf(bfhi(ws2.y), d2, a3) + G2b[4*c4+3], 0.f);
    *(float4*)(out2 + (size_t)i*64 + 4*c4) = o;
  }
}

// ---------- hw3 = out2 @ gcn3_w (64->10), thread per node ----------
__global__ __launch_bounds__(256) void k_hw3(
    const float* __restrict__ out2, const float* __restrict__ W,
    float* __restrict__ hw3, int N_)
{
  int i = blockIdx.x*256 + threadIdx.x;
  if (i >= N_) return;
  const float* row = out2 + (size_t)i*64;
  const float* __restrict__ G3 = W + O_G3;
  float a[10];
  #pragma unroll
  for (int f=0;f<10;f++) a[f] = 0.f;
  #pragma unroll 1
  for (int k=0;k<64;k++){
    float v = row[k];
    const float* __restrict__ w = G3 + k*10;
    #pragma unroll
    for (int f=0;f<10;f++) a[f] = fmaf(v, w[f], a[f]);
  }
  float* o = hw3 + (size_t)i*10;
  #pragma unroll
  for (int f=0;f<10;f++) o[f] = a[f];
}

// ---------- gcn3 aggregation + MLP head -> FP32 output ----------
// Thread per node (wave-uniform scalar weight loads). o-loop 2-wide (o, o+64).
__global__ __launch_bounds__(256) void k_final(
    const void* __restrict__ xv, const float* __restrict__ hw3,
    const int* __restrict__ rp, const int2* __restrict__ csr,
    const float* __restrict__ dis, const int* __restrict__ flags,
    const float* __restrict__ W, float* __restrict__ out, int N_)
{
  int i = blockIdx.x*256 + threadIdx.x;
  if (i >= N_) return;
  int fx = flags[0];
  float di = dis[i];
  float a[10], a2v[10];
  const float* hrow = hw3 + (size_t)i*10;
  #pragma unroll
  for (int f=0;f<10;f++){ a[f] = hrow[f]*di*di; a2v[f] = 0.f; }
  int b = rp[i], en = rp[i+1];
  int p = b;
  for (; p+3 < en; p += 4){
    int s0 = csr[p].x, s1 = csr[p+1].x, s2 = csr[p+2].x, s3 = csr[p+3].x;
    float m0 = dis[s0]*di, m1 = dis[s1]*di, m2 = dis[s2]*di, m3 = dis[s3]*di;
    const float* r0p = hw3 + (size_t)s0*10;
    const float* r1p = hw3 + (size_t)s1*10;
    const float* r2p = hw3 + (size_t)s2*10;
    const float* r3p = hw3 + (size_t)s3*10;
    #pragma unroll
    for (int f=0;f<10;f++){
      a[f]   = fmaf(r0p[f], m0, a[f]);
      a2v[f] = fmaf(r1p[f], m1, a2v[f]);
      a[f]   = fmaf(r2p[f], m2, a[f]);
      a2v[f] = fmaf(r3p[f], m3, a2v[f]);
    }
  }
  for (; p < en; p++){
    int s0 = csr[p].x; float m0 = dis[s0]*di;
    const float* r0p = hw3 + (size_t)s0*10;
    #pragma unroll
    for (int f=0;f<10;f++) a[f] = fmaf(r0p[f], m0, a[f]);
  }
  #pragma unroll
  for (int f=0;f<10;f++) a[f] += a2v[f];
  const float* G3b = W + O_G3b;
  float h20[20];
  load10_any(xv, (size_t)i, fx, h20);
  #pragma unroll
  for (int f=0;f<10;f++) h20[10+f] = fmaxf(a[f] + G3b[f], 0.f);
  const float* __restrict__ L1  = W + O_L1;
  const float* __restrict__ L1b = W + O_L1b;
  float h1[10];
  #pragma unroll
  for (int f=0;f<10;f++) h1[f] = L1b[f];
  #pragma unroll
  for (int k=0;k<20;k++){
    float v = h20[k];
    const float* __restrict__ w = L1 + k*10;
    #pragma unroll
    for (int f=0;f<10;f++) h1[f] = fmaf(v, w[f], h1[f]);
  }
  #pragma unroll
  for (int f=0;f<10;f++) h1[f] = softplusf(h1[f]);
  const float* __restrict__ L2t = W + O_L2t;
  const float* __restrict__ L2b = W + O_L2b;
  const float* __restrict__ L3  = W + O_L3;
  const float* __restrict__ L3b = W + O_L3b;
  float h3a[32], h3b[32];
  #pragma unroll
  for (int j=0;j<32;j++){ h3a[j] = L3b[j]; h3b[j] = 0.f; }
  #pragma unroll 1
  for (int o=0;o<64;o++){
    float sA = L2b[o], sB = L2b[o+64];
    const float* __restrict__ wtA = L2t + o*10;
    const float* __restrict__ wtB = L2t + (o+64)*10;
    #pragma unroll
    for (int k=0;k<10;k++){
      sA = fmaf(h1[k], wtA[k], sA);
      sB = fmaf(h1[k], wtB[k], sB);
    }
    sA = softplusf(sA);
    sB = softplusf(sB);
    const float* __restrict__ w3A = L3 + o*32;
    const float* __restrict__ w3B = L3 + (o+64)*32;
    #pragma unroll
    for (int j=0;j<32;j++){
      h3a[j] = fmaf(sA, w3A[j], h3a[j]);
      h3b[j] = fmaf(sB, w3B[j], h3b[j]);
    }
  }
  const float* L4t = W + O_L4t;
  const float* L4b = W + O_L4b;
  float r0 = L4b[0], r1 = L4b[1];
  #pragma unroll
  for (int j=0;j<32;j++){
    float h3 = softplusf(h3a[j] + h3b[j]);
    r0 = fmaf(h3, L4t[j],    r0);
    r1 = fmaf(h3, L4t[32+j], r1);
  }
  out[i]      = r0;
  out[N_ + i] = r1;
}

extern "C" void kernel_launch(void* const* d_in, const int* in_sizes, int n_in,
                              void* d_out, int out_size, void* d_ws, size_t ws_size,
                              hipStream_t stream)
{
  const void* xv  = d_in[0];
  const void* eav = d_in[1];
  const int*  ei  = (const int*)d_in[20];
  int N_ = in_sizes[0] / 10;
  int E_ = in_sizes[1] / 10;

  float* W = (float*)d_ws;
  size_t off = WTOT;
  int*   cnt   = (int*)(W + off);   off += (size_t)N_;
  int*   rp    = (int*)(W + off);   off += (size_t)N_ + 1;
  float* dis   = (float*)(W + off); off += (size_t)N_;
  int*   bsum  = (int*)(W + off);   off += 256;
  int*   boff  = (int*)(W + off);   off += 256;
  int*   flags = (int*)(W + off);   off += 32;
  off = (off + 3) & ~(size_t)3;              // 16B align
  int2*  csr   = (int2*)(W + off);  off += (size_t)E_ * 2;   // {src,dst}
  u32*   ea2   = (u32*)(W + off);   off += (size_t)E_ * 5;   // f16 edge_attr, CSR order
  float* oute  = (float*)(W + off); off += (size_t)N_ * 64;  // [N,64] f32
  float* out2  = oute;                       // reused: oute dead after k_aggxhw2
  u16*   hw2   = (u16*)(W + off);   off += (size_t)N_ * 32;  // [N,64] bf16
  float* hw3   = (float*)(W + off); off += (size_t)N_ * 10;  // [N,10] f32

  // rank: aliases oute (dead until k_edgeconv); inv: aliases hw2 (dead until k_aggxhw2)
  int* rank;
  if ((size_t)E_ <= (size_t)N_ * 64) rank = (int*)oute;
  else { rank = (int*)(W + off); off += (size_t)E_; }
  int* inv;
  if ((size_t)E_ <= (size_t)N_ * 32) inv = (int*)hw2;
  else { inv = (int*)(W + off); off += (size_t)E_; }

  if (ws_size < off * sizeof(float)) return;

  int gN = (N_ + 255)/256, gE = (E_ + 255)/256;
  int NB = (N_ + 1023)/1024;

  k_detect<<<20,256,0,stream>>>(
      (const u32*)d_in[0],(const u32*)d_in[1],
      (const u32*)d_in[2],(const u32*)d_in[3],(const u32*)d_in[4],(const u32*)d_in[5],
      (const u32*)d_in[6],(const u32*)d_in[7],(const u32*)d_in[8],(const u32*)d_in[9],
      (const u32*)d_in[10],(const u32*)d_in[11],(const u32*)d_in[12],(const u32*)d_in[13],
      (const u32*)d_in[14],(const u32*)d_in[15],(const u32*)d_in[16],(const u32*)d_in[17],
      (const u32*)d_in[18],(const u32*)d_in[19],
      flags, N_, E_);
  k_prep<<<1,256,0,stream>>>(
      d_in[2],d_in[3],d_in[4],d_in[5],d_in[6],d_in[7],d_in[8],d_in[9],
      d_in[10],d_in[11],d_in[12],d_in[13],d_in[14],d_in[15],d_in[16],d_in[17],
      d_in[18],d_in[19], flags, W);
  k_init<<<gN,256,0,stream>>>(cnt, N_);
  k_count<<<gE,256,0,stream>>>(ei, cnt, rank, E_);
  k_bsum<<<NB,1024,0,stream>>>(cnt, bsum, N_);
  k_scan_small<<<1,128,0,stream>>>(bsum, boff, NB);
  k_scan_final<<<NB,1024,0,stream>>>(cnt, boff, rp, dis, N_, E_);
  k_fillpos<<<gE,256,0,stream>>>(ei, rank, rp, inv, E_);
  k_fillcsr<<<gE,256,0,stream>>>(ei, inv, flags, eav, csr, ea2, E_);
  k_edgeconv<<<(N_+ECNB-1)/ECNB,256,0,stream>>>(xv, ea2, rp, csr, W, flags, oute, N_, E_);
  k_aggxhw2<<<gN,256,0,stream>>>(xv, rp, csr, dis, flags, oute, W, hw2, N_);
  k_agg64<<<(N_+3)/4,256,0,stream>>>(hw2, rp, csr, dis, W, out2, N_);
  k_hw3<<<gN,256,0,stream>>>(out2, W, hw3, N_);
  k_final<<<gN,256,0,stream>>>(xv, hw3, rp, csr, dis, flags, W,
                               (float*)d_out, N_);
}

// Round 13
// 618.869 us; speedup vs baseline: 1.0752x; 1.0752x over previous
//
#include <hip/hip_runtime.h>
#include <hip/hip_bf16.h>

typedef unsigned int u32;
typedef unsigned short u16;
typedef _Float16 f16;
typedef _Float16 f16x8 __attribute__((ext_vector_type(8)));
typedef float f32x4 __attribute__((ext_vector_type(4)));
typedef u32 u32x4 __attribute__((ext_vector_type(4)));

#define DEV static __device__ __forceinline__

// ---------- weight layout in ws (float offsets) ----------
#define O_G1   0        // gcn1_w  [10,64]
#define O_G1b  640      // gcn1_b  [64]
#define O_W1   704      // e_w1    [30,64]
#define O_B1   2624     // e_b1    [64]
#define O_W2   2688     // e_w2    [64,64] natural [k][o]
#define O_B2   6784     // e_b2    [64]
#define O_G2   6848     // gcn2_w  [128,64]
#define O_G2b  15040    // gcn2_b  [64]
#define O_G3   15104    // gcn3_w  [64,10]
#define O_G3b  15744    // gcn3_b  [10]
#define O_L1   15754    // l1_w    [20,10]
#define O_L1b  15954    // l1_b    [10]
#define O_L2t  15964    // l2_w^T  [128,10]
#define O_L2b  17244    // l2_b    [128]
#define O_L3   17372    // l3_w    [128,32]
#define O_L3b  21468    // l3_b    [32]
#define O_L4t  21500    // l4_w^T  [2,32]
#define O_L4b  21564    // l4_b    [2]
#define O_WF1  21568    // e_w1 f16 MFMA B-frags: 4 chunks x 64 lanes x 4 u32
#define O_WF2  22592    // e_w2 f16 MFMA B-frags: 4 chunks x 2 khalf x 4 q x 64 lanes
#define WTOT   24640

#define ECNB   32       // nodes per edgeconv block (32 -> 17.4KB LDS -> high blocks/CU)

DEV float bfu(u16 h){ return __uint_as_float(((u32)h) << 16); }
DEV float bflo(u32 u){ return __uint_as_float(u << 16); }
DEV float bfhi(u32 u){ return __uint_as_float(u & 0xffff0000u); }
DEV u16 f2bf(float x){
  __hip_bfloat16 b = __float2bfloat16(x);
  return *(u16*)&b;
}
DEV float rdf(const void* p, int idx, int isf32){
  return isf32 ? ((const float*)p)[idx] : bfu(((const u16*)p)[idx]);
}
DEV void load10_bf(const u32* __restrict__ p, float* f){
  u32 a0=p[0],a1=p[1],a2=p[2],a3=p[3],a4=p[4];
  f[0]=bflo(a0); f[1]=bfhi(a0);
  f[2]=bflo(a1); f[3]=bfhi(a1);
  f[4]=bflo(a2); f[5]=bfhi(a2);
  f[6]=bflo(a3); f[7]=bfhi(a3);
  f[8]=bflo(a4); f[9]=bfhi(a4);
}
DEV void load10_any(const void* base, size_t row, int isf32, float* f){
  if (isf32){
    const float* p = (const float*)base + row*10;
    #pragma unroll
    for (int k=0;k<10;k++) f[k] = p[k];
  } else {
    load10_bf((const u32*)base + row*5, f);
  }
}
DEV f16 load1_f16(const void* base, long idx, int isf32){
  return isf32 ? (f16)((const float*)base)[idx] : (f16)bfu(((const u16*)base)[idx]);
}
// fast softplus: log1pf is a slow libm expansion; hw exp/log are accurate enough here
DEV float softplusf(float x){ return fmaxf(x,0.f) + __logf(1.f + __expf(-fabsf(x))); }

// A-tile K permutation: k-group g=0 -> x_i[0..8), g=1 -> x_j[0..8), g=2 -> ea[0..8),
// g=3 -> x_i[8],x_i[9],x_j[8],x_j[9],ea[8],ea[9],0,0.  Maps k -> row of e_w1 (30 rows).
DEV int permk(int k){
  if (k < 8)  return k;            // x_i 0..7  -> rows 0..7
  if (k < 16) return 10 + (k-8);   // x_j 0..7  -> rows 10..17
  if (k < 24) return 20 + (k-16);  // ea  0..7  -> rows 20..27
  if (k == 24) return 8;
  if (k == 25) return 9;
  if (k == 26) return 18;
  if (k == 27) return 19;
  if (k == 28) return 28;
  if (k == 29) return 29;
  return -1;                       // k=30,31 zero pad
}
DEV u32 packh2(float a, float b){
  union { f16 h[2]; u32 u; } t;
  t.h[0] = (f16)a; t.h[1] = (f16)b;
  return t.u;
}

// ---------- dtype detection: per-array bf16 vs fp32, one block per array ----------
__global__ __launch_bounds__(256) void k_detect(
    const u32* p0, const u32* p1, const u32* p2, const u32* p3,
    const u32* p4, const u32* p5, const u32* p6, const u32* p7,
    const u32* p8, const u32* p9, const u32* p10,const u32* p11,
    const u32* p12,const u32* p13,const u32* p14,const u32* p15,
    const u32* p16,const u32* p17,const u32* p18,const u32* p19,
    int* __restrict__ flags, int N_, int E_)
{
  int a = blockIdx.x;
  const u32* p;
  int elems;
  switch (a){
    case 0:  p=p0;  elems=N_*10; break;
    case 1:  p=p1;  elems=E_*10; break;
    case 2:  p=p2;  elems=640;  break;
    case 3:  p=p3;  elems=64;   break;
    case 4:  p=p4;  elems=1920; break;
    case 5:  p=p5;  elems=64;   break;
    case 6:  p=p6;  elems=4096; break;
    case 7:  p=p7;  elems=64;   break;
    case 8:  p=p8;  elems=8192; break;
    case 9:  p=p9;  elems=64;   break;
    case 10: p=p10; elems=640;  break;
    case 11: p=p11; elems=10;   break;
    case 12: p=p12; elems=200;  break;
    case 13: p=p13; elems=10;   break;
    case 14: p=p14; elems=1280; break;
    case 15: p=p15; elems=128;  break;
    case 16: p=p16; elems=4096; break;
    case 17: p=p17; elems=32;   break;
    case 18: p=p18; elems=64;   break;
    default: p=p19; elems=2;    break;
  }
  int nw = elems/2; if (nw > 512) nw = 512; if (nw < 1) nw = 1;
  int localA = 0, localZ = 0;
  for (int i=threadIdx.x; i<nw; i+=256){
    u32 w = p[i];
    u32 ex = (w >> 7) & 0xffu;
    if (ex >= 0x90u) localA++;
    if ((w & 0xffffu) == 0u) localZ++;
  }
  int packed = (localA << 16) | localZ;
  __shared__ int red[4];
  #pragma unroll
  for (int off=32; off; off>>=1) packed += __shfl_down(packed, off);
  if ((threadIdx.x & 63) == 0) red[threadIdx.x>>6] = packed;
  __syncthreads();
  if (threadIdx.x == 0){
    int s = red[0]+red[1]+red[2]+red[3];
    int sA = s >> 16, sZ = s & 0xffff;
    flags[a] = (sA * 16 >= nw || sZ * 4 >= nw * 3) ? 1 : 0;
  }
}

// ---------- weight prep ----------
__global__ __launch_bounds__(256) void k_prep(
    const void* g1w, const void* g1b, const void* ew1, const void* eb1,
    const void* ew2, const void* eb2, const void* g2w, const void* g2b,
    const void* g3w, const void* g3b, const void* l1w, const void* l1b,
    const void* l2w, const void* l2b, const void* l3w, const void* l3b,
    const void* l4w, const void* l4b,
    const int* __restrict__ flags, float* __restrict__ W)
{
  int t = threadIdx.x;
  int f2=flags[2],f3=flags[3],f4=flags[4],f5=flags[5],f6=flags[6],f7=flags[7];
  int f8=flags[8],f9=flags[9],f10=flags[10],f11=flags[11],f12=flags[12],f13=flags[13];
  int f14=flags[14],f15=flags[15],f16=flags[16],f17=flags[17],f18=flags[18],f19=flags[19];
  for (int i=t;i<640;i+=256)  W[O_G1+i]  = rdf(g1w,i,f2);
  for (int i=t;i<64;i+=256)   W[O_G1b+i] = rdf(g1b,i,f3);
  for (int i=t;i<1920;i+=256) W[O_W1+i]  = rdf(ew1,i,f4);
  for (int i=t;i<64;i+=256)   W[O_B1+i]  = rdf(eb1,i,f5);
  for (int i=t;i<4096;i+=256) W[O_W2+i]  = rdf(ew2,i,f6);   // natural [k][o]
  for (int i=t;i<64;i+=256)   W[O_B2+i]  = rdf(eb2,i,f7);
  for (int i=t;i<8192;i+=256) W[O_G2+i]  = rdf(g2w,i,f8);
  for (int i=t;i<64;i+=256)   W[O_G2b+i] = rdf(g2b,i,f9);
  for (int i=t;i<640;i+=256)  W[O_G3+i]  = rdf(g3w,i,f10);
  for (int i=t;i<10;i+=256)   W[O_G3b+i] = rdf(g3b,i,f11);
  for (int i=t;i<200;i+=256)  W[O_L1+i]  = rdf(l1w,i,f12);
  for (int i=t;i<10;i+=256)   W[O_L1b+i] = rdf(l1b,i,f13);
  for (int i=t;i<1280;i+=256){ int o=i/10,k=i-o*10; W[O_L2t+i]=rdf(l2w,k*128+o,f14); }
  for (int i=t;i<128;i+=256)  W[O_L2b+i] = rdf(l2b,i,f15);
  for (int i=t;i<4096;i+=256) W[O_L3+i]  = rdf(l3w,i,f16);
  for (int i=t;i<32;i+=256)   W[O_L3b+i] = rdf(l3b,i,f17);
  for (int i=t;i<64;i+=256){ int c=i>>5,j=i&31; W[O_L4t+i]=rdf(l4w,j*2+c,f18); }
  for (int i=t;i<2;i+=256)    W[O_L4b+i] = rdf(l4b,i,f19);
  // e_w1 MFMA B-fragments (f16, K-permuted, padded to K=32):
  u32* Wu = (u32*)W;
  for (int i=t;i<1024;i+=256){
    int l=i&63, q=(i>>6)&3, c=i>>8;
    int k0=(l>>4)*8+2*q, col=c*16+(l&15);
    int r0=permk(k0), r1=permk(k0+1);
    float v0 = (r0<0)?0.f:rdf(ew1,r0*64+col,f4);
    float v1 = (r1<0)?0.f:rdf(ew1,r1*64+col,f4);
    Wu[O_WF1+i] = packh2(v0,v1);
  }
  // e_w2 MFMA B-fragments: k-half h, kb = 32*h + (l>>4)*8
  for (int i=t;i<2048;i+=256){
    int l=i&63, q=(i>>6)&3, h2=(i>>8)&1, c=i>>9;
    int k0=32*h2+(l>>4)*8+2*q, col=c*16+(l&15);
    Wu[O_WF2+i] = packh2(rdf(ew2,k0*64+col,f6), rdf(ew2,(k0+1)*64+col,f6));
  }
}

// ---------- init: zero cnt ----------
__global__ __launch_bounds__(256) void k_init(int* __restrict__ cnt, int N_)
{
  int i = blockIdx.x*256 + threadIdx.x;
  if (i < N_) cnt[i] = 0;
}

// ---------- degree histogram over dst + per-edge rank (coalesced write) ----------
__global__ __launch_bounds__(256) void k_count(
    const int* __restrict__ ei, int* __restrict__ cnt,
    int* __restrict__ rank, int E_)
{
  int e = blockIdx.x*256 + threadIdx.x;
  if (e >= E_) return;
  rank[e] = atomicAdd(&cnt[ei[E_+e]], 1);
}

// ---------- per-1024-block sums ----------
__global__ __launch_bounds__(1024) void k_bsum(const int* __restrict__ cnt, int* __restrict__ bsum, int N_)
{
  int i = blockIdx.x*1024 + threadIdx.x;
  int v = (i < N_) ? cnt[i] : 0;
  #pragma unroll
  for (int off=32; off; off>>=1) v += __shfl_down(v, off);
  __shared__ int ws_[16];
  if ((threadIdx.x & 63) == 0) ws_[threadIdx.x>>6] = v;
  __syncthreads();
  if (threadIdx.x == 0){
    int s = 0;
    #pragma unroll
    for (int j=0;j<16;j++) s += ws_[j];
    bsum[blockIdx.x] = s;
  }
}

// ---------- exclusive scan of block sums (NB <= 128) ----------
__global__ __launch_bounds__(128) void k_scan_small(const int* __restrict__ bsum, int* __restrict__ boff, int NB)
{
  int t = threadIdx.x;
  int v = (t < NB) ? bsum[t] : 0;
  int lane = t & 63, w = t >> 6;
  int x = v;
  #pragma unroll
  for (int off=1; off<64; off<<=1){ int y=__shfl_up(x,off); if (lane>=off) x+=y; }
  __shared__ int t2[2];
  if (lane==63) t2[w]=x;
  __syncthreads();
  if (w==1) x += t2[0];
  boff[t] = x - v;
}

// ---------- final scan: row_ptr, dis ----------
__global__ __launch_bounds__(1024) void k_scan_final(
    int* __restrict__ cnt, const int* __restrict__ boff,
    int* __restrict__ rp, float* __restrict__ dis, int N_, int E_)
{
  int i = blockIdx.x*1024 + threadIdx.x;
  int v = (i < N_) ? cnt[i] : 0;
  int lane = threadIdx.x & 63, w = threadIdx.x >> 6;
  int x = v;
  #pragma unroll
  for (int off=1; off<64; off<<=1){ int y=__shfl_up(x,off); if (lane>=off) x+=y; }
  __shared__ int wp[16];
  if (lane==63) wp[w]=x;
  __syncthreads();
  if (threadIdx.x==0){
    int run=0;
    #pragma unroll
    for (int j=0;j<16;j++){ int t=wp[j]; wp[j]=run; run+=t; }
  }
  __syncthreads();
  int incl = x + wp[w] + boff[blockIdx.x];
  if (i < N_){
    rp[i]  = incl - v;
    dis[i] = rsqrtf(1.f + (float)v);
  }
  if (i == 0) rp[N_] = E_;
}

// ---------- CSR perm fill: scatter ONLY a 4B edge id ----------
__global__ __launch_bounds__(256) void k_fillpos(
    const int* __restrict__ ei, const int* __restrict__ rank,
    const int* __restrict__ rp, int* __restrict__ inv, int E_)
{
  int e = blockIdx.x*256 + threadIdx.x;
  if (e >= E_) return;
  int d = ei[E_+e];
  inv[rp[d] + rank[e]] = e;
}

// ---------- CSR materialize: coalesced full-line int4 stream write ----------
__global__ __launch_bounds__(256) void k_fillcsr(
    const int* __restrict__ ei, const int* __restrict__ inv,
    int4* __restrict__ csr, int E_)
{
  int p = blockIdx.x*256 + threadIdx.x;
  if (p >= E_) return;
  int e = inv[p];
  csr[p] = make_int4(ei[e], e, ei[E_+e], 0);
}

// ---------- EdgeConv via MFMA: block owns ECNB nodes, waves process 16-edge CSR tiles ----------
// Index-level software pipeline: the next tile's csr int4 load is issued unconditionally
// (clamped address) before this tile's compute, taking the level-1 index latency off the
// serial chain. (Unconditional single load => compiler keeps counted vmcnt; cf. R3 failure.)
#define EC_EMIT \
  if (run >= 0){ int bb = run*64 + x; \
    atomicMax(&nodemax[bb],    __float_as_int(e0)); \
    atomicMax(&nodemax[bb+16], __float_as_int(e1)); \
    atomicMax(&nodemax[bb+32], __float_as_int(e2)); \
    atomicMax(&nodemax[bb+48], __float_as_int(e3)); }
#define EC_STEP(DD, RR) { \
  float t0=fmaxf(mcv[0][RR],0.f), t1=fmaxf(mcv[1][RR],0.f), \
        t2=fmaxf(mcv[2][RR],0.f), t3=fmaxf(mcv[3][RR],0.f); \
  if (DD == run){ e0=fmaxf(e0,t0); e1=fmaxf(e1,t1); e2=fmaxf(e2,t2); e3=fmaxf(e3,t3); } \
  else { EC_EMIT; run = DD; e0=t0; e1=t1; e2=t2; e3=t3; } }

__global__ __launch_bounds__(256) void k_edgeconv(
    const void* __restrict__ xv, const void* __restrict__ eav,
    const int* __restrict__ rp, const int4* __restrict__ csr,
    const float* __restrict__ W, const int* __restrict__ flags,
    float* __restrict__ oute, int N_, int E_)
{
  __shared__ int nodemax[ECNB*64];        // 8 KB: [local node][channel], float bits
  __shared__ u32 hbuf[4][16*36];          // per-wave h repack, 144 B row stride
  int tid = threadIdx.x;
  int l = tid & 63, wv = tid >> 6;
  int x = l & 15, g = l >> 4;
  int n0 = blockIdx.x * ECNB;
  if (n0 >= N_) return;
  int nend = n0 + ECNB; if (nend > N_) nend = N_;
  #pragma unroll
  for (int i=0;i<ECNB/4;i++) nodemax[i*256 + tid] = 0;
  int fx = flags[0], fea = flags[1];
  const u32* Wu = (const u32*)W;
  union FU { u32 u[4]; f16x8 v; };
  union HU { f16 h[8]; u32 u[4]; f16x8 v; };
  FU w1u[4];
  #pragma unroll
  for (int c=0;c<4;c++){
    #pragma unroll
    for (int q=0;q<4;q++) w1u[c].u[q] = Wu[O_WF1 + (c*4+q)*64 + l];
  }
  FU w2u[4][2];
  #pragma unroll
  for (int c=0;c<4;c++){
    #pragma unroll
    for (int h=0;h<2;h++){
      #pragma unroll
      for (int q=0;q<4;q++) w2u[c][h].u[q] = Wu[O_WF2 + ((c*2+h)*4+q)*64 + l];
    }
  }
  float b1v[4], b2v[4];
  #pragma unroll
  for (int c=0;c<4;c++){ b1v[c] = (W+O_B1)[c*16 + x]; b2v[c] = (W+O_B2)[c*16 + x]; }
  int pbase = rp[n0], pend = rp[nend];
  int ntiles = (pend - pbase + 15) >> 4;
  u32* hb = hbuf[wv];
  __syncthreads();

  // prime the index pipeline with tile wv
  int eA0 = pbase + wv*16 + x; if (eA0 > E_-1) eA0 = E_-1;
  int4 ceA = csr[eA0];

  for (int t = wv; t < ntiles; t += 4){
    int p0 = pbase + t*16;
    // ---- issue next tile's index load (unconditional, clamped) ----
    int eN = p0 + 64 + x; if (eN > E_-1) eN = E_-1;
    int4 ceB = csr[eN];
    int4 ce = ceA;                        // {src, edge, dst, 0} for this tile
    HU af;
    u32 exv = 0;                          // f16 pair of row elements 8,9
    if (g < 3){
      long row; const void* base; int isf;
      if (g==0){ row = ce.z; base = xv;  isf = fx; }
      else if (g==1){ row = ce.x; base = xv;  isf = fx; }
      else { row = ce.y; base = eav; isf = fea; }
      if (isf){
        const float* p = (const float*)base + row*10;
        #pragma unroll
        for (int j=0;j<8;j++) af.h[j] = (f16)p[j];
        exv = packh2(p[8], p[9]);
      } else {
        const u32* p = (const u32*)base + row*5;
        u32 a0=p[0],a1=p[1],a2=p[2],a3=p[3],a4=p[4];
        af.h[0]=(f16)bflo(a0); af.h[1]=(f16)bfhi(a0);
        af.h[2]=(f16)bflo(a1); af.h[3]=(f16)bfhi(a1);
        af.h[4]=(f16)bflo(a2); af.h[5]=(f16)bfhi(a2);
        af.h[6]=(f16)bflo(a3); af.h[7]=(f16)bfhi(a3);
        exv = packh2(bflo(a4), bfhi(a4));
      }
    }
    // distribute elements 8..9 of the three rows of edge x to the g=3 lanes
    u32 ge0 = (u32)__shfl((int)exv, x);        // from g=0 lane: x_dst[8..9]
    u32 ge1 = (u32)__shfl((int)exv, x+16);     // from g=1 lane: x_src[8..9]
    u32 ge2 = (u32)__shfl((int)exv, x+32);     // from g=2 lane: ea[8..9]
    if (g == 3){ af.u[0]=ge0; af.u[1]=ge1; af.u[2]=ge2; af.u[3]=0; }
    // dst ids for this lane's 4 output edges via shfl of already-loaded ce.z
    int pe = p0 + 4*g;
    int dz = ce.z;
    int d0 = __shfl(dz, 4*g+0); d0 = (pe   < pend) ? d0 - n0 : -1;
    int d1 = __shfl(dz, 4*g+1); d1 = (pe+1 < pend) ? d1 - n0 : -1;
    int d2 = __shfl(dz, 4*g+2); d2 = (pe+2 < pend) ? d2 - n0 : -1;
    int d3 = __shfl(dz, 4*g+3); d3 = (pe+3 < pend) ? d3 - n0 : -1;
    // layer 1: h[16,64]
    f32x4 z = {0.f,0.f,0.f,0.f};
    f32x4 hc[4];
    #pragma unroll
    for (int c=0;c<4;c++)
      hc[c] = __builtin_amdgcn_mfma_f32_16x16x32_f16(af.v, w1u[c].v, z, 0, 0, 0);
    // bias+relu, pack f16 pairs across lane^1, write C-layout -> LDS rows
    #pragma unroll
    for (int r=0;r<4;r++){
      u32 pk0,pk1,pk2,pk3;
      {
        float hv = fmaxf(hc[0][r] + b1v[0], 0.f);
        union { f16 h; u16 u; } cv; cv.h=(f16)hv; u32 mine=cv.u;
        u32 other=(u32)__shfl_xor((int)mine,1,64);
        pk0 = (x&1) ? (other|(mine<<16)) : (mine|(other<<16));
      }{
        float hv = fmaxf(hc[1][r] + b1v[1], 0.f);
        union { f16 h; u16 u; } cv; cv.h=(f16)hv; u32 mine=cv.u;
        u32 other=(u32)__shfl_xor((int)mine,1,64);
        pk1 = (x&1) ? (other|(mine<<16)) : (mine|(other<<16));
      }{
        float hv = fmaxf(hc[2][r] + b1v[2], 0.f);
        union { f16 h; u16 u; } cv; cv.h=(f16)hv; u32 mine=cv.u;
        u32 other=(u32)__shfl_xor((int)mine,1,64);
        pk2 = (x&1) ? (other|(mine<<16)) : (mine|(other<<16));
      }{
        float hv = fmaxf(hc[3][r] + b1v[3], 0.f);
        union { f16 h; u16 u; } cv; cv.h=(f16)hv; u32 mine=cv.u;
        u32 other=(u32)__shfl_xor((int)mine,1,64);
        pk3 = (x&1) ? (other|(mine<<16)) : (mine|(other<<16));
      }
      int edge = 4*g + r;
      int par = (x&1) ? 16 : 0;
      hb[edge*36 + par + (x>>1)]     = (x&1) ? pk2 : pk0;   // chunks 0 / 2
      hb[edge*36 + 8 + par + (x>>1)] = (x&1) ? pk3 : pk1;   // chunks 1 / 3
    }
    asm volatile("s_waitcnt lgkmcnt(0)" ::: "memory");
    // read A2 fragments: row = x (edge), k = g*8 + 32*half
    HU a2f[2];
    #pragma unroll
    for (int h=0;h<2;h++){
      const u32x4* p = (const u32x4*)&hb[x*36 + g*4 + 16*h];
      u32x4 tv = *p;
      a2f[h].u[0]=tv[0]; a2f[h].u[1]=tv[1]; a2f[h].u[2]=tv[2]; a2f[h].u[3]=tv[3];
    }
    // layer 2: m[16,64] with bias in C-init
    f32x4 mcv[4];
    #pragma unroll
    for (int c=0;c<4;c++){
      f32x4 bi = {b2v[c],b2v[c],b2v[c],b2v[c]};
      f32x4 acc = __builtin_amdgcn_mfma_f32_16x16x32_f16(a2f[0].v, w2u[c][0].v, bi, 0, 0, 0);
      mcv[c]    = __builtin_amdgcn_mfma_f32_16x16x32_f16(a2f[1].v, w2u[c][1].v, acc, 0, 0, 0);
    }
    // CSR-run-merged segmented max into LDS node table
    int run = -2; float e0=0.f,e1=0.f,e2=0.f,e3=0.f;
    EC_STEP(d0,0) EC_STEP(d1,1) EC_STEP(d2,2) EC_STEP(d3,3)
    EC_EMIT;
    // rotate index pipeline
    ceA = ceB;
  }
  __syncthreads();
  int tot = (nend - n0) * 64;
  for (int i = tid; i < tot; i += 256)
    oute[(size_t)n0*64 + i] = __int_as_float(nodemax[i]);
}

// ---------- FUSED gcn1 pre-agg + hw2: gather phase + MLP phase in one thread ----------
// Thread per node keeps all weight access wave-uniform (scalar loads). The two phases
// have opposite bottlenecks (gather = latency, MLP = VALU) so desynced waves overlap.
__global__ __launch_bounds__(256) void k_aggxhw2(
    const void* __restrict__ xv, const int* __restrict__ rp,
    const int4* __restrict__ csr, const float* __restrict__ dis,
    const int* __restrict__ flags, const float* __restrict__ oute,
    const float* __restrict__ W, u16* __restrict__ hw2o, int N_)
{
  int i = blockIdx.x*256 + threadIdx.x;
  if (i >= N_) return;
  int fx = flags[0];
  float di = dis[i], d2 = di*di;
  // ---- gather: sv = S*x row (stays in registers) ----
  float sv[10], ac2[10], tA[10], tB[10], tC[10], tD[10];
  load10_any(xv, (size_t)i, fx, tA);
  #pragma unroll
  for (int f=0;f<10;f++){ sv[f] = tA[f]*d2; ac2[f] = 0.f; }
  int b = rp[i], en = rp[i+1];
  int p = b;
  for (; p+3 < en; p += 4){
    int s0 = csr[p].x, s1 = csr[p+1].x, s2 = csr[p+2].x, s3 = csr[p+3].x;
    float m0 = dis[s0]*di, m1 = dis[s1]*di, m2 = dis[s2]*di, m3 = dis[s3]*di;
    load10_any(xv, (size_t)s0, fx, tA);
    load10_any(xv, (size_t)s1, fx, tB);
    load10_any(xv, (size_t)s2, fx, tC);
    load10_any(xv, (size_t)s3, fx, tD);
    #pragma unroll
    for (int f=0;f<10;f++){
      sv[f]  = fmaf(tA[f], m0, sv[f]);
      ac2[f] = fmaf(tB[f], m1, ac2[f]);
      sv[f]  = fmaf(tC[f], m2, sv[f]);
      ac2[f] = fmaf(tD[f], m3, ac2[f]);
    }
  }
  for (; p < en; p++){
    int s0 = csr[p].x; float m0 = dis[s0]*di;
    load10_any(xv, (size_t)s0, fx, tA);
    #pragma unroll
    for (int f=0;f<10;f++) sv[f] = fmaf(tA[f], m0, sv[f]);
  }
  #pragma unroll
  for (int f=0;f<10;f++) sv[f] += ac2[f];
  // ---- MLP: hw2 = relu(sv@G1+G1b)@G2top + oute@G2bot -> bf16 ----
  const float* __restrict__ G1  = W + O_G1;
  const float* __restrict__ G1b = W + O_G1b;
  const float* __restrict__ G2  = W + O_G2;
  float hw[64];
  #pragma unroll
  for (int f=0;f<64;f++) hw[f] = 0.f;
  #pragma unroll 1
  for (int k=0;k<64;k++){
    float o1 = G1b[k];
    #pragma unroll
    for (int j=0;j<10;j++) o1 = fmaf(sv[j], G1[j*64+k], o1);
    o1 = fmaxf(o1, 0.f);
    const float* __restrict__ wt = G2 + k*64;
    #pragma unroll
    for (int f=0;f<64;f++) hw[f] = fmaf(o1, wt[f], hw[f]);
  }
  const float* orow = oute + (size_t)i*64;
  #pragma unroll 1
  for (int k=0;k<64;k++){
    float ov = orow[k];
    const float* __restrict__ wb = G2 + (64+k)*64;
    #pragma unroll
    for (int f=0;f<64;f++) hw[f] = fmaf(ov, wb[f], hw[f]);
  }
  u16* out = hw2o + (size_t)i*64;
  #pragma unroll
  for (int f=0;f<64;f++) out[f] = f2bf(hw[f]);
}

// ---------- gcn2 aggregation: wave per node, 16 lanes x 4 edge slots, uint2 loads ----------
__global__ __launch_bounds__(256) void k_agg64(
    const u16* __restrict__ hw2, const int* __restrict__ rp,
    const int4* __restrict__ csr, const float* __restrict__ dis,
    const float* __restrict__ W, float* __restrict__ out2, int N_)
{
  int i = (blockIdx.x*256 + threadIdx.x) >> 6;
  int lane = threadIdx.x & 63;
  if (i >= N_) return;
  int e4 = lane >> 4, c4 = lane & 15;
  float di = dis[i];
  int b = rp[i], en = rp[i+1];
  const uint2* __restrict__ h2 = (const uint2*)hw2;   // row stride = 16 uint2
  float a0=0.f,a1=0.f,a2=0.f,a3=0.f;
  float b0=0.f,b1=0.f,b2=0.f,b3=0.f;
  int p = b + e4;
  int sA = (p   < en) ? csr[p].x   : 0;
  int sB = (p+4 < en) ? csr[p+4].x : 0;
  for (; p + 4 < en; p += 8){
    int sAn = (p+8  < en) ? csr[p+8].x  : 0;
    int sBn = (p+12 < en) ? csr[p+12].x : 0;
    float nmA = dis[sA]*di, nmB = dis[sB]*di;
    uint2 wA = h2[(size_t)sA*16 + c4];
    uint2 wB = h2[(size_t)sB*16 + c4];
    a0 = fmaf(bflo(wA.x), nmA, a0); a1 = fmaf(bfhi(wA.x), nmA, a1);
    a2 = fmaf(bflo(wA.y), nmA, a2); a3 = fmaf(bfhi(wA.y), nmA, a3);
    b0 = fmaf(bflo(wB.x), nmB, b0); b1 = fmaf(bfhi(wB.x), nmB, b1);
    b2 = fmaf(bflo(wB.y), nmB, b2); b3 = fmaf(bfhi(wB.y), nmB, b3);
    sA = sAn; sB = sBn;
  }
  if (p < en){
    float nmA = dis[sA]*di;
    uint2 wA = h2[(size_t)sA*16 + c4];
    a0 = fmaf(bflo(wA.x), nmA, a0); a1 = fmaf(bfhi(wA.x), nmA, a1);
    a2 = fmaf(bflo(wA.y), nmA, a2); a3 = fmaf(bfhi(wA.y), nmA, a3);
  }
  a0 += b0; a1 += b1; a2 += b2; a3 += b3;
  a0 += __shfl_xor(a0,16); a1 += __shfl_xor(a1,16);
  a2 += __shfl_xor(a2,16); a3 += __shfl_xor(a3,16);
  a0 += __shfl_xor(a0,32); a1 += __shfl_xor(a1,32);
  a2 += __shfl_xor(a2,32); a3 += __shfl_xor(a3,32);
  if (e4 == 0){
    uint2 ws2 = h2[(size_t)i*16 + c4];
    float d2 = di*di;
    const float* G2b = W + O_G2b;
    float4 o;
    o.x = fmaxf(fmaf(bflo(ws2.x), d2, a0) + G2b[4*c4],   0.f);
    o.y = fmaxf(fmaf(bfhi(ws2.x), d2, a1) + G2b[4*c4+1], 0.f);
    o.z = fmaxf(fmaf(bflo(ws2.y), d2, a2) + G2b[4*c4+2], 0.f);
    o.w = fmaxf(fmaf(bfhi(ws2.y), d2, a3) + G2b[4*c4+3], 0.f);
    *(float4*)(out2 + (size_t)i*64 + 4*c4) = o;
  }
}

// ---------- hw3 = out2 @ gcn3_w (64->10), thread per node ----------
__global__ __launch_bounds__(256) void k_hw3(
    const float* __restrict__ out2, const float* __restrict__ W,
    float* __restrict__ hw3, int N_)
{
  int i = blockIdx.x*256 + threadIdx.x;
  if (i >= N_) return;
  const float* row = out2 + (size_t)i*64;
  const float* __restrict__ G3 = W + O_G3;
  float a[10];
  #pragma unroll
  for (int f=0;f<10;f++) a[f] = 0.f;
  #pragma unroll 1
  for (int k=0;k<64;k++){
    float v = row[k];
    const float* __restrict__ w = G3 + k*10;
    #pragma unroll
    for (int f=0;f<10;f++) a[f] = fmaf(v, w[f], a[f]);
  }
  float* o = hw3 + (size_t)i*10;
  #pragma unroll
  for (int f=0;f<10;f++) o[f] = a[f];
}

// ---------- gcn3 aggregation + MLP head -> FP32 output ----------
// Thread per node (wave-uniform scalar weight loads). o-loop 2-wide (o, o+64).
__global__ __launch_bounds__(256) void k_final(
    const void* __restrict__ xv, const float* __restrict__ hw3,
    const int* __restrict__ rp, const int4* __restrict__ csr,
    const float* __restrict__ dis, const int* __restrict__ flags,
    const float* __restrict__ W, float* __restrict__ out, int N_)
{
  int i = blockIdx.x*256 + threadIdx.x;
  if (i >= N_) return;
  int fx = flags[0];
  float di = dis[i];
  float a[10], a2v[10];
  const float* hrow = hw3 + (size_t)i*10;
  #pragma unroll
  for (int f=0;f<10;f++){ a[f] = hrow[f]*di*di; a2v[f] = 0.f; }
  int b = rp[i], en = rp[i+1];
  int p = b;
  for (; p+3 < en; p += 4){
    int s0 = csr[p].x, s1 = csr[p+1].x, s2 = csr[p+2].x, s3 = csr[p+3].x;
    float m0 = dis[s0]*di, m1 = dis[s1]*di, m2 = dis[s2]*di, m3 = dis[s3]*di;
    const float* r0p = hw3 + (size_t)s0*10;
    const float* r1p = hw3 + (size_t)s1*10;
    const float* r2p = hw3 + (size_t)s2*10;
    const float* r3p = hw3 + (size_t)s3*10;
    #pragma unroll
    for (int f=0;f<10;f++){
      a[f]   = fmaf(r0p[f], m0, a[f]);
      a2v[f] = fmaf(r1p[f], m1, a2v[f]);
      a[f]   = fmaf(r2p[f], m2, a[f]);
      a2v[f] = fmaf(r3p[f], m3, a2v[f]);
    }
  }
  for (; p < en; p++){
    int s0 = csr[p].x; float m0 = dis[s0]*di;
    const float* r0p = hw3 + (size_t)s0*10;
    #pragma unroll
    for (int f=0;f<10;f++) a[f] = fmaf(r0p[f], m0, a[f]);
  }
  #pragma unroll
  for (int f=0;f<10;f++) a[f] += a2v[f];
  const float* G3b = W + O_G3b;
  float h20[20];
  load10_any(xv, (size_t)i, fx, h20);
  #pragma unroll
  for (int f=0;f<10;f++) h20[10+f] = fmaxf(a[f] + G3b[f], 0.f);
  const float* __restrict__ L1  = W + O_L1;
  const float* __restrict__ L1b = W + O_L1b;
  float h1[10];
  #pragma unroll
  for (int f=0;f<10;f++) h1[f] = L1b[f];
  #pragma unroll
  for (int k=0;k<20;k++){
    float v = h20[k];
    const float* __restrict__ w = L1 + k*10;
    #pragma unroll
    for (int f=0;f<10;f++) h1[f] = fmaf(v, w[f], h1[f]);
  }
  #pragma unroll
  for (int f=0;f<10;f++) h1[f] = softplusf(h1[f]);
  const float* __restrict__ L2t = W + O_L2t;
  const float* __restrict__ L2b = W + O_L2b;
  const float* __restrict__ L3  = W + O_L3;
  const float* __restrict__ L3b = W + O_L3b;
  float h3a[32], h3b[32];
  #pragma unroll
  for (int j=0;j<32;j++){ h3a[j] = L3b[j]; h3b[j] = 0.f; }
  #pragma unroll 1
  for (int o=0;o<64;o++){
    float sA = L2b[o], sB = L2b[o+64];
    const float* __restrict__ wtA = L2t + o*10;
    const float* __restrict__ wtB = L2t + (o+64)*10;
    #pragma unroll
    for (int k=0;k<10;k++){
      sA = fmaf(h1[k], wtA[k], sA);
      sB = fmaf(h1[k], wtB[k], sB);
    }
    sA = softplusf(sA);
    sB = softplusf(sB);
    const float* __restrict__ w3A = L3 + o*32;
    const float* __restrict__ w3B = L3 + (o+64)*32;
    #pragma unroll
    for (int j=0;j<32;j++){
      h3a[j] = fmaf(sA, w3A[j], h3a[j]);
      h3b[j] = fmaf(sB, w3B[j], h3b[j]);
    }
  }
  const float* L4t = W + O_L4t;
  const float* L4b = W + O_L4b;
  float r0 = L4b[0], r1 = L4b[1];
  #pragma unroll
  for (int j=0;j<32;j++){
    float h3 = softplusf(h3a[j] + h3b[j]);
    r0 = fmaf(h3, L4t[j],    r0);
    r1 = fmaf(h3, L4t[32+j], r1);
  }
  out[i]      = r0;
  out[N_ + i] = r1;
}

extern "C" void kernel_launch(void* const* d_in, const int* in_sizes, int n_in,
                              void* d_out, int out_size, void* d_ws, size_t ws_size,
                              hipStream_t stream)
{
  const void* xv  = d_in[0];
  const void* eav = d_in[1];
  const int*  ei  = (const int*)d_in[20];
  int N_ = in_sizes[0] / 10;
  int E_ = in_sizes[1] / 10;

  float* W = (float*)d_ws;
  size_t off = WTOT;
  int*   cnt   = (int*)(W + off);   off += (size_t)N_;
  int*   rp    = (int*)(W + off);   off += (size_t)N_ + 1;
  float* dis   = (float*)(W + off); off += (size_t)N_;
  int*   bsum  = (int*)(W + off);   off += 256;
  int*   boff  = (int*)(W + off);   off += 256;
  int*   flags = (int*)(W + off);   off += 32;
  off = (off + 3) & ~(size_t)3;              // 16B align for int4 csr
  int4*  csr   = (int4*)(W + off);  off += (size_t)E_ * 4;
  float* oute  = (float*)(W + off); off += (size_t)N_ * 64;   // [N,64] f32
  float* out2  = oute;                       // reused: oute dead after k_aggxhw2
  u16*   hw2   = (u16*)(W + off);   off += (size_t)N_ * 32;   // [N,64] bf16
  float* hw3   = (float*)(W + off); off += (size_t)N_ * 10;   // [N,10] f32

  // rank: aliases oute (dead until k_edgeconv); inv: aliases hw2 (dead until k_aggxhw2)
  int* rank;
  if ((size_t)E_ <= (size_t)N_ * 64) rank = (int*)oute;
  else { rank = (int*)(W + off); off += (size_t)E_; }
  int* inv;
  if ((size_t)E_ <= (size_t)N_ * 32) inv = (int*)hw2;
  else { inv = (int*)(W + off); off += (size_t)E_; }

  if (ws_size < off * sizeof(float)) return;

  int gN = (N_ + 255)/256, gE = (E_ + 255)/256;
  int NB = (N_ + 1023)/1024;

  k_detect<<<20,256,0,stream>>>(
      (const u32*)d_in[0],(const u32*)d_in[1],
      (const u32*)d_in[2],(const u32*)d_in[3],(const u32*)d_in[4],(const u32*)d_in[5],
      (const u32*)d_in[6],(const u32*)d_in[7],(const u32*)d_in[8],(const u32*)d_in[9],
      (const u32*)d_in[10],(const u32*)d_in[11],(const u32*)d_in[12],(const u32*)d_in[13],
      (const u32*)d_in[14],(const u32*)d_in[15],(const u32*)d_in[16],(const u32*)d_in[17],
      (const u32*)d_in[18],(const u32*)d_in[19],
      flags, N_, E_);
  k_prep<<<1,256,0,stream>>>(
      d_in[2],d_in[3],d_in[4],d_in[5],d_in[6],d_in[7],d_in[8],d_in[9],
      d_in[10],d_in[11],d_in[12],d_in[13],d_in[14],d_in[15],d_in[16],d_in[17],
      d_in[18],d_in[19], flags, W);
  k_init<<<gN,256,0,stream>>>(cnt, N_);
  k_count<<<gE,256,0,stream>>>(ei, cnt, rank, E_);
  k_bsum<<<NB,1024,0,stream>>>(cnt, bsum, N_);
  k_scan_small<<<1,128,0,stream>>>(bsum, boff, NB);
  k_scan_final<<<NB,1024,0,stream>>>(cnt, boff, rp, dis, N_, E_);
  k_fillpos<<<gE,256,0,stream>>>(ei, rank, rp, inv, E_);
  k_fillcsr<<<gE,256,0,stream>>>(ei, inv, csr, E_);
  k_edgeconv<<<(N_+ECNB-1)/ECNB,256,0,stream>>>(xv, eav, rp, csr, W, flags, oute, N_, E_);
  k_aggxhw2<<<gN,256,0,stream>>>(xv, rp, csr, dis, flags, oute, W, hw2, N_);
  k_agg64<<<(N_+3)/4,256,0,stream>>>(hw2, rp, csr, dis, W, out2, N_);
  k_hw3<<<gN,256,0,stream>>>(out2, W, hw3, N_);
  k_final<<<gN,256,0,stream>>>(xv, hw3, rp, csr, dis, flags, W,
                               (float*)d_out, N_);
}

// Round 14
// 618.410 us; speedup vs baseline: 1.0760x; 1.0007x over previous
//
#include <hip/hip_runtime.h>
#include <hip/hip_bf16.h>

typedef unsigned int u32;
typedef unsigned short u16;
typedef _Float16 f16;
typedef _Float16 f16x8 __attribute__((ext_vector_type(8)));
typedef float f32x4 __attribute__((ext_vector_type(4)));
typedef u32 u32x4 __attribute__((ext_vector_type(4)));

#define DEV static __device__ __forceinline__

// ---------- weight layout in ws (float offsets) ----------
#define O_G1   0        // gcn1_w  [10,64]
#define O_G1b  640      // gcn1_b  [64]
#define O_W1   704      // e_w1    [30,64]
#define O_B1   2624     // e_b1    [64]
#define O_W2   2688     // e_w2    [64,64] natural [k][o]
#define O_B2   6784     // e_b2    [64]
#define O_G2   6848     // gcn2_w  [128,64]
#define O_G2b  15040    // gcn2_b  [64]
#define O_G3   15104    // gcn3_w  [64,10]
#define O_G3b  15744    // gcn3_b  [10]
#define O_L1   15754    // l1_w    [20,10]
#define O_L1b  15954    // l1_b    [10]
#define O_L2t  15964    // l2_w^T  [128,10]
#define O_L2b  17244    // l2_b    [128]
#define O_L3   17372    // l3_w    [128,32]
#define O_L3b  21468    // l3_b    [32]
#define O_L4t  21500    // l4_w^T  [2,32]
#define O_L4b  21564    // l4_b    [2]
#define O_WF1  21568    // e_w1 f16 MFMA B-frags: 4 chunks x 64 lanes x 4 u32
#define O_WF2  22592    // e_w2 f16 MFMA B-frags: 4 chunks x 2 khalf x 4 q x 64 lanes
#define WTOT   24640

#define ECNB   32       // nodes per edgeconv block (32 -> 17.4KB LDS -> high blocks/CU)

DEV float bfu(u16 h){ return __uint_as_float(((u32)h) << 16); }
DEV float bflo(u32 u){ return __uint_as_float(u << 16); }
DEV float bfhi(u32 u){ return __uint_as_float(u & 0xffff0000u); }
DEV u16 f2bf(float x){
  __hip_bfloat16 b = __float2bfloat16(x);
  return *(u16*)&b;
}
DEV float rdf(const void* p, int idx, int isf32){
  return isf32 ? ((const float*)p)[idx] : bfu(((const u16*)p)[idx]);
}
DEV void load10_bf(const u32* __restrict__ p, float* f){
  u32 a0=p[0],a1=p[1],a2=p[2],a3=p[3],a4=p[4];
  f[0]=bflo(a0); f[1]=bfhi(a0);
  f[2]=bflo(a1); f[3]=bfhi(a1);
  f[4]=bflo(a2); f[5]=bfhi(a2);
  f[6]=bflo(a3); f[7]=bfhi(a3);
  f[8]=bflo(a4); f[9]=bfhi(a4);
}
DEV void load10_any(const void* base, size_t row, int isf32, float* f){
  if (isf32){
    const float* p = (const float*)base + row*10;
    #pragma unroll
    for (int k=0;k<10;k++) f[k] = p[k];
  } else {
    load10_bf((const u32*)base + row*5, f);
  }
}
// fast softplus: log1pf is a slow libm expansion; hw exp/log are accurate enough here
DEV float softplusf(float x){ return fmaxf(x,0.f) + __logf(1.f + __expf(-fabsf(x))); }

// A-tile K permutation: k-group g=0 -> x_i[0..8), g=1 -> x_j[0..8), g=2 -> ea[0..8),
// g=3 -> x_i[8],x_i[9],x_j[8],x_j[9],ea[8],ea[9],0,0.  Maps k -> row of e_w1 (30 rows).
DEV int permk(int k){
  if (k < 8)  return k;            // x_i 0..7  -> rows 0..7
  if (k < 16) return 10 + (k-8);   // x_j 0..7  -> rows 10..17
  if (k < 24) return 20 + (k-16);  // ea  0..7  -> rows 20..27
  if (k == 24) return 8;
  if (k == 25) return 9;
  if (k == 26) return 18;
  if (k == 27) return 19;
  if (k == 28) return 28;
  if (k == 29) return 29;
  return -1;                       // k=30,31 zero pad
}
DEV u32 packh2(float a, float b){
  union { f16 h[2]; u32 u; } t;
  t.h[0] = (f16)a; t.h[1] = (f16)b;
  return t.u;
}

// ---------- dtype detection: per-array bf16 vs fp32, one block per array ----------
__global__ __launch_bounds__(256) void k_detect(
    const u32* p0, const u32* p1, const u32* p2, const u32* p3,
    const u32* p4, const u32* p5, const u32* p6, const u32* p7,
    const u32* p8, const u32* p9, const u32* p10,const u32* p11,
    const u32* p12,const u32* p13,const u32* p14,const u32* p15,
    const u32* p16,const u32* p17,const u32* p18,const u32* p19,
    int* __restrict__ flags, int N_, int E_)
{
  int a = blockIdx.x;
  const u32* p;
  int elems;
  switch (a){
    case 0:  p=p0;  elems=N_*10; break;
    case 1:  p=p1;  elems=E_*10; break;
    case 2:  p=p2;  elems=640;  break;
    case 3:  p=p3;  elems=64;   break;
    case 4:  p=p4;  elems=1920; break;
    case 5:  p=p5;  elems=64;   break;
    case 6:  p=p6;  elems=4096; break;
    case 7:  p=p7;  elems=64;   break;
    case 8:  p=p8;  elems=8192; break;
    case 9:  p=p9;  elems=64;   break;
    case 10: p=p10; elems=640;  break;
    case 11: p=p11; elems=10;   break;
    case 12: p=p12; elems=200;  break;
    case 13: p=p13; elems=10;   break;
    case 14: p=p14; elems=1280; break;
    case 15: p=p15; elems=128;  break;
    case 16: p=p16; elems=4096; break;
    case 17: p=p17; elems=32;   break;
    case 18: p=p18; elems=64;   break;
    default: p=p19; elems=2;    break;
  }
  int nw = elems/2; if (nw > 512) nw = 512; if (nw < 1) nw = 1;
  int localA = 0, localZ = 0;
  for (int i=threadIdx.x; i<nw; i+=256){
    u32 w = p[i];
    u32 ex = (w >> 7) & 0xffu;
    if (ex >= 0x90u) localA++;
    if ((w & 0xffffu) == 0u) localZ++;
  }
  int packed = (localA << 16) | localZ;
  __shared__ int red[4];
  #pragma unroll
  for (int off=32; off; off>>=1) packed += __shfl_down(packed, off);
  if ((threadIdx.x & 63) == 0) red[threadIdx.x>>6] = packed;
  __syncthreads();
  if (threadIdx.x == 0){
    int s = red[0]+red[1]+red[2]+red[3];
    int sA = s >> 16, sZ = s & 0xffff;
    flags[a] = (sA * 16 >= nw || sZ * 4 >= nw * 3) ? 1 : 0;
  }
}

// ---------- weight prep ----------
__global__ __launch_bounds__(256) void k_prep(
    const void* g1w, const void* g1b, const void* ew1, const void* eb1,
    const void* ew2, const void* eb2, const void* g2w, const void* g2b,
    const void* g3w, const void* g3b, const void* l1w, const void* l1b,
    const void* l2w, const void* l2b, const void* l3w, const void* l3b,
    const void* l4w, const void* l4b,
    const int* __restrict__ flags, float* __restrict__ W)
{
  int t = threadIdx.x;
  int f2=flags[2],f3=flags[3],f4=flags[4],f5=flags[5],f6=flags[6],f7=flags[7];
  int f8=flags[8],f9=flags[9],f10=flags[10],f11=flags[11],f12=flags[12],f13=flags[13];
  int f14=flags[14],f15=flags[15],f16=flags[16],f17=flags[17],f18=flags[18],f19=flags[19];
  for (int i=t;i<640;i+=256)  W[O_G1+i]  = rdf(g1w,i,f2);
  for (int i=t;i<64;i+=256)   W[O_G1b+i] = rdf(g1b,i,f3);
  for (int i=t;i<1920;i+=256) W[O_W1+i]  = rdf(ew1,i,f4);
  for (int i=t;i<64;i+=256)   W[O_B1+i]  = rdf(eb1,i,f5);
  for (int i=t;i<4096;i+=256) W[O_W2+i]  = rdf(ew2,i,f6);   // natural [k][o]
  for (int i=t;i<64;i+=256)   W[O_B2+i]  = rdf(eb2,i,f7);
  for (int i=t;i<8192;i+=256) W[O_G2+i]  = rdf(g2w,i,f8);
  for (int i=t;i<64;i+=256)   W[O_G2b+i] = rdf(g2b,i,f9);
  for (int i=t;i<640;i+=256)  W[O_G3+i]  = rdf(g3w,i,f10);
  for (int i=t;i<10;i+=256)   W[O_G3b+i] = rdf(g3b,i,f11);
  for (int i=t;i<200;i+=256)  W[O_L1+i]  = rdf(l1w,i,f12);
  for (int i=t;i<10;i+=256)   W[O_L1b+i] = rdf(l1b,i,f13);
  for (int i=t;i<1280;i+=256){ int o=i/10,k=i-o*10; W[O_L2t+i]=rdf(l2w,k*128+o,f14); }
  for (int i=t;i<128;i+=256)  W[O_L2b+i] = rdf(l2b,i,f15);
  for (int i=t;i<4096;i+=256) W[O_L3+i]  = rdf(l3w,i,f16);
  for (int i=t;i<32;i+=256)   W[O_L3b+i] = rdf(l3b,i,f17);
  for (int i=t;i<64;i+=256){ int c=i>>5,j=i&31; W[O_L4t+i]=rdf(l4w,j*2+c,f18); }
  for (int i=t;i<2;i+=256)    W[O_L4b+i] = rdf(l4b,i,f19);
  // e_w1 MFMA B-fragments (f16, K-permuted, padded to K=32):
  u32* Wu = (u32*)W;
  for (int i=t;i<1024;i+=256){
    int l=i&63, q=(i>>6)&3, c=i>>8;
    int k0=(l>>4)*8+2*q, col=c*16+(l&15);
    int r0=permk(k0), r1=permk(k0+1);
    float v0 = (r0<0)?0.f:rdf(ew1,r0*64+col,f4);
    float v1 = (r1<0)?0.f:rdf(ew1,r1*64+col,f4);
    Wu[O_WF1+i] = packh2(v0,v1);
  }
  // e_w2 MFMA B-fragments: k-half h, kb = 32*h + (l>>4)*8
  for (int i=t;i<2048;i+=256){
    int l=i&63, q=(i>>6)&3, h2=(i>>8)&1, c=i>>9;
    int k0=32*h2+(l>>4)*8+2*q, col=c*16+(l&15);
    Wu[O_WF2+i] = packh2(rdf(ew2,k0*64+col,f6), rdf(ew2,(k0+1)*64+col,f6));
  }
}

// ---------- init: zero cnt ----------
__global__ __launch_bounds__(256) void k_init(int* __restrict__ cnt, int N_)
{
  int i = blockIdx.x*256 + threadIdx.x;
  if (i < N_) cnt[i] = 0;
}

// ---------- degree histogram over dst + per-edge rank (coalesced write) ----------
__global__ __launch_bounds__(256) void k_count(
    const int* __restrict__ ei, int* __restrict__ cnt,
    int* __restrict__ rank, int E_)
{
  int e = blockIdx.x*256 + threadIdx.x;
  if (e >= E_) return;
  rank[e] = atomicAdd(&cnt[ei[E_+e]], 1);
}

// ---------- per-1024-block sums ----------
__global__ __launch_bounds__(1024) void k_bsum(const int* __restrict__ cnt, int* __restrict__ bsum, int N_)
{
  int i = blockIdx.x*1024 + threadIdx.x;
  int v = (i < N_) ? cnt[i] : 0;
  #pragma unroll
  for (int off=32; off; off>>=1) v += __shfl_down(v, off);
  __shared__ int ws_[16];
  if ((threadIdx.x & 63) == 0) ws_[threadIdx.x>>6] = v;
  __syncthreads();
  if (threadIdx.x == 0){
    int s = 0;
    #pragma unroll
    for (int j=0;j<16;j++) s += ws_[j];
    bsum[blockIdx.x] = s;
  }
}

// ---------- exclusive scan of block sums (NB <= 128) ----------
__global__ __launch_bounds__(128) void k_scan_small(const int* __restrict__ bsum, int* __restrict__ boff, int NB)
{
  int t = threadIdx.x;
  int v = (t < NB) ? bsum[t] : 0;
  int lane = t & 63, w = t >> 6;
  int x = v;
  #pragma unroll
  for (int off=1; off<64; off<<=1){ int y=__shfl_up(x,off); if (lane>=off) x+=y; }
  __shared__ int t2[2];
  if (lane==63) t2[w]=x;
  __syncthreads();
  if (w==1) x += t2[0];
  boff[t] = x - v;
}

// ---------- final scan: row_ptr, dis ----------
__global__ __launch_bounds__(1024) void k_scan_final(
    int* __restrict__ cnt, const int* __restrict__ boff,
    int* __restrict__ rp, float* __restrict__ dis, int N_, int E_)
{
  int i = blockIdx.x*1024 + threadIdx.x;
  int v = (i < N_) ? cnt[i] : 0;
  int lane = threadIdx.x & 63, w = threadIdx.x >> 6;
  int x = v;
  #pragma unroll
  for (int off=1; off<64; off<<=1){ int y=__shfl_up(x,off); if (lane>=off) x+=y; }
  __shared__ int wp[16];
  if (lane==63) wp[w]=x;
  __syncthreads();
  if (threadIdx.x==0){
    int run=0;
    #pragma unroll
    for (int j=0;j<16;j++){ int t=wp[j]; wp[j]=run; run+=t; }
  }
  __syncthreads();
  int incl = x + wp[w] + boff[blockIdx.x];
  if (i < N_){
    rp[i]  = incl - v;
    dis[i] = rsqrtf(1.f + (float)v);
  }
  if (i == 0) rp[N_] = E_;
}

// ---------- CSR perm fill: scatter ONLY a 4B edge id ----------
__global__ __launch_bounds__(256) void k_fillpos(
    const int* __restrict__ ei, const int* __restrict__ rank,
    const int* __restrict__ rp, int* __restrict__ inv, int E_)
{
  int e = blockIdx.x*256 + threadIdx.x;
  if (e >= E_) return;
  int d = ei[E_+e];
  inv[rp[d] + rank[e]] = e;
}

// ---------- CSR materialize: coalesced full-line int4 stream write ----------
__global__ __launch_bounds__(256) void k_fillcsr(
    const int* __restrict__ ei, const int* __restrict__ inv,
    int4* __restrict__ csr, int E_)
{
  int p = blockIdx.x*256 + threadIdx.x;
  if (p >= E_) return;
  int e = inv[p];
  csr[p] = make_int4(ei[e], e, ei[E_+e], 0);
}

// ---------- EdgeConv via MFMA: block owns ECNB nodes, waves process 16-edge CSR tiles ----------
// Index-level software pipeline: the next tile's csr int4 load is issued unconditionally
// (clamped address) before this tile's compute.
#define EC_EMIT \
  if (run >= 0){ int bb = run*64 + x; \
    atomicMax(&nodemax[bb],    __float_as_int(e0)); \
    atomicMax(&nodemax[bb+16], __float_as_int(e1)); \
    atomicMax(&nodemax[bb+32], __float_as_int(e2)); \
    atomicMax(&nodemax[bb+48], __float_as_int(e3)); }
#define EC_STEP(DD, RR) { \
  float t0=fmaxf(mcv[0][RR],0.f), t1=fmaxf(mcv[1][RR],0.f), \
        t2=fmaxf(mcv[2][RR],0.f), t3=fmaxf(mcv[3][RR],0.f); \
  if (DD == run){ e0=fmaxf(e0,t0); e1=fmaxf(e1,t1); e2=fmaxf(e2,t2); e3=fmaxf(e3,t3); } \
  else { EC_EMIT; run = DD; e0=t0; e1=t1; e2=t2; e3=t3; } }

__global__ __launch_bounds__(256) void k_edgeconv(
    const void* __restrict__ xv, const void* __restrict__ eav,
    const int* __restrict__ rp, const int4* __restrict__ csr,
    const float* __restrict__ W, const int* __restrict__ flags,
    float* __restrict__ oute, int N_, int E_)
{
  __shared__ int nodemax[ECNB*64];        // 8 KB: [local node][channel], float bits
  __shared__ u32 hbuf[4][16*36];          // per-wave h repack, 144 B row stride
  int tid = threadIdx.x;
  int l = tid & 63, wv = tid >> 6;
  int x = l & 15, g = l >> 4;
  int n0 = blockIdx.x * ECNB;
  if (n0 >= N_) return;
  int nend = n0 + ECNB; if (nend > N_) nend = N_;
  #pragma unroll
  for (int i=0;i<ECNB/4;i++) nodemax[i*256 + tid] = 0;
  int fx = flags[0], fea = flags[1];
  const u32* Wu = (const u32*)W;
  union FU { u32 u[4]; f16x8 v; };
  union HU { f16 h[8]; u32 u[4]; f16x8 v; };
  FU w1u[4];
  #pragma unroll
  for (int c=0;c<4;c++){
    #pragma unroll
    for (int q=0;q<4;q++) w1u[c].u[q] = Wu[O_WF1 + (c*4+q)*64 + l];
  }
  FU w2u[4][2];
  #pragma unroll
  for (int c=0;c<4;c++){
    #pragma unroll
    for (int h=0;h<2;h++){
      #pragma unroll
      for (int q=0;q<4;q++) w2u[c][h].u[q] = Wu[O_WF2 + ((c*2+h)*4+q)*64 + l];
    }
  }
  float b1v[4], b2v[4];
  #pragma unroll
  for (int c=0;c<4;c++){ b1v[c] = (W+O_B1)[c*16 + x]; b2v[c] = (W+O_B2)[c*16 + x]; }
  int pbase = rp[n0], pend = rp[nend];
  int ntiles = (pend - pbase + 15) >> 4;
  u32* hb = hbuf[wv];
  __syncthreads();

  // prime the index pipeline with tile wv
  int eA0 = pbase + wv*16 + x; if (eA0 > E_-1) eA0 = E_-1;
  int4 ceA = csr[eA0];

  for (int t = wv; t < ntiles; t += 4){
    int p0 = pbase + t*16;
    // ---- issue next tile's index load (unconditional, clamped) ----
    int eN = p0 + 64 + x; if (eN > E_-1) eN = E_-1;
    int4 ceB = csr[eN];
    int4 ce = ceA;                        // {src, edge, dst, 0} for this tile
    HU af;
    u32 exv = 0;                          // f16 pair of row elements 8,9
    if (g < 3){
      long row; const void* base; int isf;
      if (g==0){ row = ce.z; base = xv;  isf = fx; }
      else if (g==1){ row = ce.x; base = xv;  isf = fx; }
      else { row = ce.y; base = eav; isf = fea; }
      if (isf){
        const float* p = (const float*)base + row*10;
        #pragma unroll
        for (int j=0;j<8;j++) af.h[j] = (f16)p[j];
        exv = packh2(p[8], p[9]);
      } else {
        const u32* p = (const u32*)base + row*5;
        u32 a0=p[0],a1=p[1],a2=p[2],a3=p[3],a4=p[4];
        af.h[0]=(f16)bflo(a0); af.h[1]=(f16)bfhi(a0);
        af.h[2]=(f16)bflo(a1); af.h[3]=(f16)bfhi(a1);
        af.h[4]=(f16)bflo(a2); af.h[5]=(f16)bfhi(a2);
        af.h[6]=(f16)bflo(a3); af.h[7]=(f16)bfhi(a3);
        exv = packh2(bflo(a4), bfhi(a4));
      }
    }
    // distribute elements 8..9 of the three rows of edge x to the g=3 lanes
    u32 ge0 = (u32)__shfl((int)exv, x);        // from g=0 lane: x_dst[8..9]
    u32 ge1 = (u32)__shfl((int)exv, x+16);     // from g=1 lane: x_src[8..9]
    u32 ge2 = (u32)__shfl((int)exv, x+32);     // from g=2 lane: ea[8..9]
    if (g == 3){ af.u[0]=ge0; af.u[1]=ge1; af.u[2]=ge2; af.u[3]=0; }
    // dst ids for this lane's 4 output edges via shfl of already-loaded ce.z
    int pe = p0 + 4*g;
    int dz = ce.z;
    int d0 = __shfl(dz, 4*g+0); d0 = (pe   < pend) ? d0 - n0 : -1;
    int d1 = __shfl(dz, 4*g+1); d1 = (pe+1 < pend) ? d1 - n0 : -1;
    int d2 = __shfl(dz, 4*g+2); d2 = (pe+2 < pend) ? d2 - n0 : -1;
    int d3 = __shfl(dz, 4*g+3); d3 = (pe+3 < pend) ? d3 - n0 : -1;
    // layer 1: h[16,64]
    f32x4 z = {0.f,0.f,0.f,0.f};
    f32x4 hc[4];
    #pragma unroll
    for (int c=0;c<4;c++)
      hc[c] = __builtin_amdgcn_mfma_f32_16x16x32_f16(af.v, w1u[c].v, z, 0, 0, 0);
    // bias+relu, pack f16 pairs across lane^1, write C-layout -> LDS rows
    #pragma unroll
    for (int r=0;r<4;r++){
      u32 pk0,pk1,pk2,pk3;
      {
        float hv = fmaxf(hc[0][r] + b1v[0], 0.f);
        union { f16 h; u16 u; } cv; cv.h=(f16)hv; u32 mine=cv.u;
        u32 other=(u32)__shfl_xor((int)mine,1,64);
        pk0 = (x&1) ? (other|(mine<<16)) : (mine|(other<<16));
      }{
        float hv = fmaxf(hc[1][r] + b1v[1], 0.f);
        union { f16 h; u16 u; } cv; cv.h=(f16)hv; u32 mine=cv.u;
        u32 other=(u32)__shfl_xor((int)mine,1,64);
        pk1 = (x&1) ? (other|(mine<<16)) : (mine|(other<<16));
      }{
        float hv = fmaxf(hc[2][r] + b1v[2], 0.f);
        union { f16 h; u16 u; } cv; cv.h=(f16)hv; u32 mine=cv.u;
        u32 other=(u32)__shfl_xor((int)mine,1,64);
        pk2 = (x&1) ? (other|(mine<<16)) : (mine|(other<<16));
      }{
        float hv = fmaxf(hc[3][r] + b1v[3], 0.f);
        union { f16 h; u16 u; } cv; cv.h=(f16)hv; u32 mine=cv.u;
        u32 other=(u32)__shfl_xor((int)mine,1,64);
        pk3 = (x&1) ? (other|(mine<<16)) : (mine|(other<<16));
      }
      int edge = 4*g + r;
      int par = (x&1) ? 16 : 0;
      hb[edge*36 + par + (x>>1)]     = (x&1) ? pk2 : pk0;   // chunks 0 / 2
      hb[edge*36 + 8 + par + (x>>1)] = (x&1) ? pk3 : pk1;   // chunks 1 / 3
    }
    asm volatile("s_waitcnt lgkmcnt(0)" ::: "memory");
    // read A2 fragments: row = x (edge), k = g*8 + 32*half
    HU a2f[2];
    #pragma unroll
    for (int h=0;h<2;h++){
      const u32x4* p = (const u32x4*)&hb[x*36 + g*4 + 16*h];
      u32x4 tv = *p;
      a2f[h].u[0]=tv[0]; a2f[h].u[1]=tv[1]; a2f[h].u[2]=tv[2]; a2f[h].u[3]=tv[3];
    }
    // layer 2: m[16,64] with bias in C-init
    f32x4 mcv[4];
    #pragma unroll
    for (int c=0;c<4;c++){
      f32x4 bi = {b2v[c],b2v[c],b2v[c],b2v[c]};
      f32x4 acc = __builtin_amdgcn_mfma_f32_16x16x32_f16(a2f[0].v, w2u[c][0].v, bi, 0, 0, 0);
      mcv[c]    = __builtin_amdgcn_mfma_f32_16x16x32_f16(a2f[1].v, w2u[c][1].v, acc, 0, 0, 0);
    }
    // CSR-run-merged segmented max into LDS node table
    int run = -2; float e0=0.f,e1=0.f,e2=0.f,e3=0.f;
    EC_STEP(d0,0) EC_STEP(d1,1) EC_STEP(d2,2) EC_STEP(d3,3)
    EC_EMIT;
    // rotate index pipeline
    ceA = ceB;
  }
  __syncthreads();
  int tot = (nend - n0) * 64;
  for (int i = tid; i < tot; i += 256)
    oute[(size_t)n0*64 + i] = __int_as_float(nodemax[i]);
}

// ---------- FUSED gcn1 pre-agg + hw2: gather phase + MLP phase in one thread ----------
// Index-pipelined gather: next iteration's 4 csr indices prefetched (clamped) while the
// current rows are gathered; removes the idx->row serial latency at 19% occupancy.
__global__ __launch_bounds__(256) void k_aggxhw2(
    const void* __restrict__ xv, const int* __restrict__ rp,
    const int4* __restrict__ csr, const float* __restrict__ dis,
    const int* __restrict__ flags, const float* __restrict__ oute,
    const float* __restrict__ W, u16* __restrict__ hw2o, int N_)
{
  int i = blockIdx.x*256 + threadIdx.x;
  if (i >= N_) return;
  int fx = flags[0];
  float di = dis[i], d2 = di*di;
  // ---- gather: sv = S*x row (stays in registers) ----
  float sv[10], ac2[10], tA[10], tB[10], tC[10], tD[10];
  load10_any(xv, (size_t)i, fx, tA);
  #pragma unroll
  for (int f=0;f<10;f++){ sv[f] = tA[f]*d2; ac2[f] = 0.f; }
  int b = rp[i], en = rp[i+1];
  int last = (en > b) ? (en-1) : b;
  int p = b;
  int i0 = csr[min(p,   last)].x;
  int i1 = csr[min(p+1, last)].x;
  int i2 = csr[min(p+2, last)].x;
  int i3 = csr[min(p+3, last)].x;
  for (; p+3 < en; p += 4){
    int j0 = csr[min(p+4, last)].x;
    int j1 = csr[min(p+5, last)].x;
    int j2 = csr[min(p+6, last)].x;
    int j3 = csr[min(p+7, last)].x;
    float m0 = dis[i0]*di, m1 = dis[i1]*di, m2 = dis[i2]*di, m3 = dis[i3]*di;
    load10_any(xv, (size_t)i0, fx, tA);
    load10_any(xv, (size_t)i1, fx, tB);
    load10_any(xv, (size_t)i2, fx, tC);
    load10_any(xv, (size_t)i3, fx, tD);
    #pragma unroll
    for (int f=0;f<10;f++){
      sv[f]  = fmaf(tA[f], m0, sv[f]);
      ac2[f] = fmaf(tB[f], m1, ac2[f]);
      sv[f]  = fmaf(tC[f], m2, sv[f]);
      ac2[f] = fmaf(tD[f], m3, ac2[f]);
    }
    i0=j0; i1=j1; i2=j2; i3=j3;
  }
  for (; p < en; p++){
    int s0 = csr[p].x; float m0 = dis[s0]*di;
    load10_any(xv, (size_t)s0, fx, tA);
    #pragma unroll
    for (int f=0;f<10;f++) sv[f] = fmaf(tA[f], m0, sv[f]);
  }
  #pragma unroll
  for (int f=0;f<10;f++) sv[f] += ac2[f];
  // ---- MLP: hw2 = relu(sv@G1+G1b)@G2top + oute@G2bot -> bf16 ----
  const float* __restrict__ G1  = W + O_G1;
  const float* __restrict__ G1b = W + O_G1b;
  const float* __restrict__ G2  = W + O_G2;
  float hw[64];
  #pragma unroll
  for (int f=0;f<64;f++) hw[f] = 0.f;
  #pragma unroll 1
  for (int k=0;k<64;k++){
    float o1 = G1b[k];
    #pragma unroll
    for (int j=0;j<10;j++) o1 = fmaf(sv[j], G1[j*64+k], o1);
    o1 = fmaxf(o1, 0.f);
    const float* __restrict__ wt = G2 + k*64;
    #pragma unroll
    for (int f=0;f<64;f++) hw[f] = fmaf(o1, wt[f], hw[f]);
  }
  const float* orow = oute + (size_t)i*64;
  #pragma unroll 1
  for (int k=0;k<64;k++){
    float ov = orow[k];
    const float* __restrict__ wb = G2 + (64+k)*64;
    #pragma unroll
    for (int f=0;f<64;f++) hw[f] = fmaf(ov, wb[f], hw[f]);
  }
  u16* out = hw2o + (size_t)i*64;
  #pragma unroll
  for (int f=0;f<64;f++) out[f] = f2bf(hw[f]);
}

// ---------- gcn2 aggregation: wave per node, 16 lanes x 4 edge slots, uint2 loads ----------
__global__ __launch_bounds__(256) void k_agg64(
    const u16* __restrict__ hw2, const int* __restrict__ rp,
    const int4* __restrict__ csr, const float* __restrict__ dis,
    const float* __restrict__ W, float* __restrict__ out2, int N_)
{
  int i = (blockIdx.x*256 + threadIdx.x) >> 6;
  int lane = threadIdx.x & 63;
  if (i >= N_) return;
  int e4 = lane >> 4, c4 = lane & 15;
  float di = dis[i];
  int b = rp[i], en = rp[i+1];
  const uint2* __restrict__ h2 = (const uint2*)hw2;   // row stride = 16 uint2
  float a0=0.f,a1=0.f,a2=0.f,a3=0.f;
  float b0=0.f,b1=0.f,b2=0.f,b3=0.f;
  int p = b + e4;
  int sA = (p   < en) ? csr[p].x   : 0;
  int sB = (p+4 < en) ? csr[p+4].x : 0;
  for (; p + 4 < en; p += 8){
    int sAn = (p+8  < en) ? csr[p+8].x  : 0;
    int sBn = (p+12 < en) ? csr[p+12].x : 0;
    float nmA = dis[sA]*di, nmB = dis[sB]*di;
    uint2 wA = h2[(size_t)sA*16 + c4];
    uint2 wB = h2[(size_t)sB*16 + c4];
    a0 = fmaf(bflo(wA.x), nmA, a0); a1 = fmaf(bfhi(wA.x), nmA, a1);
    a2 = fmaf(bflo(wA.y), nmA, a2); a3 = fmaf(bfhi(wA.y), nmA, a3);
    b0 = fmaf(bflo(wB.x), nmB, b0); b1 = fmaf(bfhi(wB.x), nmB, b1);
    b2 = fmaf(bflo(wB.y), nmB, b2); b3 = fmaf(bfhi(wB.y), nmB, b3);
    sA = sAn; sB = sBn;
  }
  if (p < en){
    float nmA = dis[sA]*di;
    uint2 wA = h2[(size_t)sA*16 + c4];
    a0 = fmaf(bflo(wA.x), nmA, a0); a1 = fmaf(bfhi(wA.x), nmA, a1);
    a2 = fmaf(bflo(wA.y), nmA, a2); a3 = fmaf(bfhi(wA.y), nmA, a3);
  }
  a0 += b0; a1 += b1; a2 += b2; a3 += b3;
  a0 += __shfl_xor(a0,16); a1 += __shfl_xor(a1,16);
  a2 += __shfl_xor(a2,16); a3 += __shfl_xor(a3,16);
  a0 += __shfl_xor(a0,32); a1 += __shfl_xor(a1,32);
  a2 += __shfl_xor(a2,32); a3 += __shfl_xor(a3,32);
  if (e4 == 0){
    uint2 ws2 = h2[(size_t)i*16 + c4];
    float d2 = di*di;
    const float* G2b = W + O_G2b;
    float4 o;
    o.x = fmaxf(fmaf(bflo(ws2.x), d2, a0) + G2b[4*c4],   0.f);
    o.y = fmaxf(fmaf(bfhi(ws2.x), d2, a1) + G2b[4*c4+1], 0.f);
    o.z = fmaxf(fmaf(bflo(ws2.y), d2, a2) + G2b[4*c4+2], 0.f);
    o.w = fmaxf(fmaf(bfhi(ws2.y), d2, a3) + G2b[4*c4+3], 0.f);
    *(float4*)(out2 + (size_t)i*64 + 4*c4) = o;
  }
}

// ---------- hw3 = out2 @ gcn3_w (64->10), thread per node ----------
__global__ __launch_bounds__(256) void k_hw3(
    const float* __restrict__ out2, const float* __restrict__ W,
    float* __restrict__ hw3, int N_)
{
  int i = blockIdx.x*256 + threadIdx.x;
  if (i >= N_) return;
  const float* row = out2 + (size_t)i*64;
  const float* __restrict__ G3 = W + O_G3;
  float a[10];
  #pragma unroll
  for (int f=0;f<10;f++) a[f] = 0.f;
  #pragma unroll 1
  for (int k=0;k<64;k++){
    float v = row[k];
    const float* __restrict__ w = G3 + k*10;
    #pragma unroll
    for (int f=0;f<10;f++) a[f] = fmaf(v, w[f], a[f]);
  }
  float* o = hw3 + (size_t)i*10;
  #pragma unroll
  for (int f=0;f<10;f++) o[f] = a[f];
}

// ---------- gcn3 aggregation + MLP head -> FP32 output ----------
// Thread per node (wave-uniform scalar weight loads). o-loop 2-wide (o, o+64).
// Index-pipelined gather (same pattern as k_aggxhw2).
__global__ __launch_bounds__(256) void k_final(
    const void* __restrict__ xv, const float* __restrict__ hw3,
    const int* __restrict__ rp, const int4* __restrict__ csr,
    const float* __restrict__ dis, const int* __restrict__ flags,
    const float* __restrict__ W, float* __restrict__ out, int N_)
{
  int i = blockIdx.x*256 + threadIdx.x;
  if (i >= N_) return;
  int fx = flags[0];
  float di = dis[i];
  float a[10], a2v[10];
  const float* hrow = hw3 + (size_t)i*10;
  #pragma unroll
  for (int f=0;f<10;f++){ a[f] = hrow[f]*di*di; a2v[f] = 0.f; }
  int b = rp[i], en = rp[i+1];
  int last = (en > b) ? (en-1) : b;
  int p = b;
  int i0 = csr[min(p,   last)].x;
  int i1 = csr[min(p+1, last)].x;
  int i2 = csr[min(p+2, last)].x;
  int i3 = csr[min(p+3, last)].x;
  for (; p+3 < en; p += 4){
    int j0 = csr[min(p+4, last)].x;
    int j1 = csr[min(p+5, last)].x;
    int j2 = csr[min(p+6, last)].x;
    int j3 = csr[min(p+7, last)].x;
    float m0 = dis[i0]*di, m1 = dis[i1]*di, m2 = dis[i2]*di, m3 = dis[i3]*di;
    const float* r0p = hw3 + (size_t)i0*10;
    const float* r1p = hw3 + (size_t)i1*10;
    const float* r2p = hw3 + (size_t)i2*10;
    const float* r3p = hw3 + (size_t)i3*10;
    #pragma unroll
    for (int f=0;f<10;f++){
      a[f]   = fmaf(r0p[f], m0, a[f]);
      a2v[f] = fmaf(r1p[f], m1, a2v[f]);
      a[f]   = fmaf(r2p[f], m2, a[f]);
      a2v[f] = fmaf(r3p[f], m3, a2v[f]);
    }
    i0=j0; i1=j1; i2=j2; i3=j3;
  }
  for (; p < en; p++){
    int s0 = csr[p].x; float m0 = dis[s0]*di;
    const float* r0p = hw3 + (size_t)s0*10;
    #pragma unroll
    for (int f=0;f<10;f++) a[f] = fmaf(r0p[f], m0, a[f]);
  }
  #pragma unroll
  for (int f=0;f<10;f++) a[f] += a2v[f];
  const float* G3b = W + O_G3b;
  float h20[20];
  load10_any(xv, (size_t)i, fx, h20);
  #pragma unroll
  for (int f=0;f<10;f++) h20[10+f] = fmaxf(a[f] + G3b[f], 0.f);
  const float* __restrict__ L1  = W + O_L1;
  const float* __restrict__ L1b = W + O_L1b;
  float h1[10];
  #pragma unroll
  for (int f=0;f<10;f++) h1[f] = L1b[f];
  #pragma unroll
  for (int k=0;k<20;k++){
    float v = h20[k];
    const float* __restrict__ w = L1 + k*10;
    #pragma unroll
    for (int f=0;f<10;f++) h1[f] = fmaf(v, w[f], h1[f]);
  }
  #pragma unroll
  for (int f=0;f<10;f++) h1[f] = softplusf(h1[f]);
  const float* __restrict__ L2t = W + O_L2t;
  const float* __restrict__ L2b = W + O_L2b;
  const float* __restrict__ L3  = W + O_L3;
  const float* __restrict__ L3b = W + O_L3b;
  float h3a[32], h3b[32];
  #pragma unroll
  for (int j=0;j<32;j++){ h3a[j] = L3b[j]; h3b[j] = 0.f; }
  #pragma unroll 1
  for (int o=0;o<64;o++){
    float sA = L2b[o], sB = L2b[o+64];
    const float* __restrict__ wtA = L2t + o*10;
    const float* __restrict__ wtB = L2t + (o+64)*10;
    #pragma unroll
    for (int k=0;k<10;k++){
      sA = fmaf(h1[k], wtA[k], sA);
      sB = fmaf(h1[k], wtB[k], sB);
    }
    sA = softplusf(sA);
    sB = softplusf(sB);
    const float* __restrict__ w3A = L3 + o*32;
    const float* __restrict__ w3B = L3 + (o+64)*32;
    #pragma unroll
    for (int j=0;j<32;j++){
      h3a[j] = fmaf(sA, w3A[j], h3a[j]);
      h3b[j] = fmaf(sB, w3B[j], h3b[j]);
    }
  }
  const float* L4t = W + O_L4t;
  const float* L4b = W + O_L4b;
  float r0 = L4b[0], r1 = L4b[1];
  #pragma unroll
  for (int j=0;j<32;j++){
    float h3 = softplusf(h3a[j] + h3b[j]);
    r0 = fmaf(h3, L4t[j],    r0);
    r1 = fmaf(h3, L4t[32+j], r1);
  }
  out[i]      = r0;
  out[N_ + i] = r1;
}

extern "C" void kernel_launch(void* const* d_in, const int* in_sizes, int n_in,
                              void* d_out, int out_size, void* d_ws, size_t ws_size,
                              hipStream_t stream)
{
  const void* xv  = d_in[0];
  const void* eav = d_in[1];
  const int*  ei  = (const int*)d_in[20];
  int N_ = in_sizes[0] / 10;
  int E_ = in_sizes[1] / 10;

  float* W = (float*)d_ws;
  size_t off = WTOT;
  int*   cnt   = (int*)(W + off);   off += (size_t)N_;
  int*   rp    = (int*)(W + off);   off += (size_t)N_ + 1;
  float* dis   = (float*)(W + off); off += (size_t)N_;
  int*   bsum  = (int*)(W + off);   off += 256;
  int*   boff  = (int*)(W + off);   off += 256;
  int*   flags = (int*)(W + off);   off += 32;
  off = (off + 3) & ~(size_t)3;              // 16B align for int4 csr
  int4*  csr   = (int4*)(W + off);  off += (size_t)E_ * 4;
  float* oute  = (float*)(W + off); off += (size_t)N_ * 64;   // [N,64] f32
  float* out2  = oute;                       // reused: oute dead after k_aggxhw2
  u16*   hw2   = (u16*)(W + off);   off += (size_t)N_ * 32;   // [N,64] bf16
  float* hw3   = (float*)(W + off); off += (size_t)N_ * 10;   // [N,10] f32

  // rank: aliases oute (dead until k_edgeconv); inv: aliases hw2 (dead until k_aggxhw2)
  int* rank;
  if ((size_t)E_ <= (size_t)N_ * 64) rank = (int*)oute;
  else { rank = (int*)(W + off); off += (size_t)E_; }
  int* inv;
  if ((size_t)E_ <= (size_t)N_ * 32) inv = (int*)hw2;
  else { inv = (int*)(W + off); off += (size_t)E_; }

  if (ws_size < off * sizeof(float)) return;

  int gN = (N_ + 255)/256, gE = (E_ + 255)/256;
  int NB = (N_ + 1023)/1024;

  k_detect<<<20,256,0,stream>>>(
      (const u32*)d_in[0],(const u32*)d_in[1],
      (const u32*)d_in[2],(const u32*)d_in[3],(const u32*)d_in[4],(const u32*)d_in[5],
      (const u32*)d_in[6],(const u32*)d_in[7],(const u32*)d_in[8],(const u32*)d_in[9],
      (const u32*)d_in[10],(const u32*)d_in[11],(const u32*)d_in[12],(const u32*)d_in[13],
      (const u32*)d_in[14],(const u32*)d_in[15],(const u32*)d_in[16],(const u32*)d_in[17],
      (const u32*)d_in[18],(const u32*)d_in[19],
      flags, N_, E_);
  k_prep<<<1,256,0,stream>>>(
      d_in[2],d_in[3],d_in[4],d_in[5],d_in[6],d_in[7],d_in[8],d_in[9],
      d_in[10],d_in[11],d_in[12],d_in[13],d_in[14],d_in[15],d_in[16],d_in[17],
      d_in[18],d_in[19], flags, W);
  k_init<<<gN,256,0,stream>>>(cnt, N_);
  k_count<<<gE,256,0,stream>>>(ei, cnt, rank, E_);
  k_bsum<<<NB,1024,0,stream>>>(cnt, bsum, N_);
  k_scan_small<<<1,128,0,stream>>>(bsum, boff, NB);
  k_scan_final<<<NB,1024,0,stream>>>(cnt, boff, rp, dis, N_, E_);
  k_fillpos<<<gE,256,0,stream>>>(ei, rank, rp, inv, E_);
  k_fillcsr<<<gE,256,0,stream>>>(ei, inv, csr, E_);
  k_edgeconv<<<(N_+ECNB-1)/ECNB,256,0,stream>>>(xv, eav, rp, csr, W, flags, oute, N_, E_);
  k_aggxhw2<<<gN,256,0,stream>>>(xv, rp, csr, dis, flags, oute, W, hw2, N_);
  k_agg64<<<(N_+3)/4,256,0,stream>>>(hw2, rp, csr, dis, W, out2, N_);
  k_hw3<<<gN,256,0,stream>>>(out2, W, hw3, N_);
  k_final<<<gN,256,0,stream>>>(xv, hw3, rp, csr, dis, flags, W,
                               (float*)d_out, N_);
}